// Round 8
// baseline (223.212 us; speedup 1.0000x reference)
//
#include <hip/hip_runtime.h>
#include <hip/hip_bf16.h>

// Problem constants (ConvBertSelfAttention): B=4, S=2048, H=8, D=64, K=9
#define NH   8
#define HD   64
#define KW   9
#define AD   512      // H*D
#define HIDD 1024     // 2*A
#define BB   4
#define SS   2048
#define MTOK (BB*SS)  // 8192 tokens
#define WSZ  262144   // 512*512 weight elements

typedef __attribute__((ext_vector_type(8))) short short8;    // 8 bf16 (4 VGPRs)
typedef __attribute__((ext_vector_type(4))) float floatx4;   // 16x16 MFMA C/D
typedef __attribute__((ext_vector_type(16))) float floatx16; // 32x32 MFMA C/D

__device__ __forceinline__ short f2bf(float f) {
    unsigned u = __float_as_uint(f);
    u = (u + 0x7FFFu + ((u >> 16) & 1u)) >> 16;
    return (short)u;
}
__device__ __forceinline__ float bf2f(short s) {
    return __uint_as_float(((unsigned)(unsigned short)s) << 16);
}
// raw v_exp_f32 (2^x)
__device__ __forceinline__ float exp2_raw(float x) {
    return __builtin_amdgcn_exp2f(x);
}
// pack two floats to two bf16: a -> low16, b -> high16 (RNE, 1 instr)
__device__ __forceinline__ unsigned pkbf2(float a, float b) {
    unsigned d;
    asm("v_cvt_pk_bf16_f32 %0, %1, %2" : "=v"(d) : "v"(a), "v"(b));
    return d;
}
// async global->LDS, 16 B per lane; LDS dest = wave-uniform base + lane*16
__device__ __forceinline__ void gl2lds16(const short* g, short* l) {
    __builtin_amdgcn_global_load_lds(
        (const __attribute__((address_space(1))) void*)g,
        (__attribute__((address_space(3))) void*)l, 16, 0, 0);
}

// ---------------------------------------------------------------------------
// prep kernel: fused {hs fp32->bf16 | weights fp32->bf16 | depthwise conv}.
// Block ranges: [0,4096) cvt_hs, [4096,4768) cvt_w, [4768,6816) dwconv.
// ---------------------------------------------------------------------------
__global__ __launch_bounds__(256) void prep_kernel(
    const float* __restrict__ hs,
    const float* __restrict__ pw, const float* __restrict__ Wco,
    const float* __restrict__ Wq, const float* __restrict__ Wk,
    const float* __restrict__ Wv, const float* __restrict__ Wck,
    const float* __restrict__ dw,
    short* __restrict__ hsb, short* __restrict__ wb, short* __restrict__ x1)
{
    __shared__ float wl[KW * AD];            // 18 KB (dwconv branch only)
    const int bid = blockIdx.x, tid = threadIdx.x;

    if (bid < 4096) {
        // ---- cvt_hs: MTOK x 1024 fp32 -> bf16, 8 elem/thread ----
        int idx = bid * 256 + tid;
        const float* s = hs + (long)idx * 8;
        float4 a = *(const float4*)s, c = *(const float4*)(s + 4);
        short8 o;
        o[0]=f2bf(a.x); o[1]=f2bf(a.y); o[2]=f2bf(a.z); o[3]=f2bf(a.w);
        o[4]=f2bf(c.x); o[5]=f2bf(c.y); o[6]=f2bf(c.z); o[7]=f2bf(c.w);
        *(short8*)(hsb + (long)idx * 8) = o;
    } else if (bid < 4768) {
        // ---- cvt_w: [pw][Wco][Wq][Wk][Wv][Wck padded 128x512] ----
        int idx = (bid - 4096) * 256 + tid;  // [0, 172032)
        int e0 = idx * 8;
        short8 o;
        if (e0 < 5 * WSZ) {
            int w = e0 >> 18, off = e0 & (WSZ - 1);
            const float* src = (w == 0) ? pw : (w == 1) ? Wco : (w == 2) ? Wq
                             : (w == 3) ? Wk : Wv;
            float4 a = *(const float4*)(src + off), c = *(const float4*)(src + off + 4);
            o[0]=f2bf(a.x); o[1]=f2bf(a.y); o[2]=f2bf(a.z); o[3]=f2bf(a.w);
            o[4]=f2bf(c.x); o[5]=f2bf(c.y); o[6]=f2bf(c.z); o[7]=f2bf(c.w);
        } else {
            int off = e0 - 5 * WSZ;          // 0 .. 65535 over 128x512
            int row = off >> 9, col = off & 511;
            if (row < NH * KW) {
                const float* src = Wck + row * AD + col;
                float4 a = *(const float4*)src, c = *(const float4*)(src + 4);
                o[0]=f2bf(a.x); o[1]=f2bf(a.y); o[2]=f2bf(a.z); o[3]=f2bf(a.w);
                o[4]=f2bf(c.x); o[5]=f2bf(c.y); o[6]=f2bf(c.z); o[7]=f2bf(c.w);
            } else {
                for (int i = 0; i < 8; ++i) o[i] = 0;
            }
        }
        *(short8*)(wb + e0) = o;
    } else {
        // ---- dwconv: 8 ch/thread, fp32 inputs, dw staged transposed ----
        for (int t = tid; t < KW * AD; t += 256) {
            int c = t / KW, k = t - c * KW;  // dw linear = [c][k]
            wl[k * AD + c] = dw[t];
        }
        __syncthreads();
        int idx = (bid - 4768) * 256 + tid;  // over MTOK*AD/8
        int c8  = (idx & 63) * 8;
        int tok = idx >> 6;
        int s   = tok & (SS - 1);
        int b   = tok >> 11;
        const float* base = hs + (long)(b * SS) * HIDD + AD + c8;
        float acc[8];
#pragma unroll
        for (int i = 0; i < 8; ++i) acc[i] = 0.f;
#pragma unroll
        for (int kk = 0; kk < KW; ++kk) {
            int ss2 = s + kk - KW / 2;
            if (ss2 >= 0 && ss2 < SS) {
                const float* hp = base + (long)ss2 * HIDD;
                float4 h0 = *(const float4*)hp;
                float4 h1 = *(const float4*)(hp + 4);
                float4 w0 = *(const float4*)(wl + kk * AD + c8);
                float4 w1 = *(const float4*)(wl + kk * AD + c8 + 4);
                acc[0] += w0.x * h0.x; acc[1] += w0.y * h0.y;
                acc[2] += w0.z * h0.z; acc[3] += w0.w * h0.w;
                acc[4] += w1.x * h1.x; acc[5] += w1.y * h1.y;
                acc[6] += w1.z * h1.z; acc[7] += w1.w * h1.w;
            }
        }
        short8 o;
#pragma unroll
        for (int i = 0; i < 8; ++i) o[i] = f2bf(acc[i]);
        *(short8*)(x1 + (long)tok * AD + c8) = o;
    }
}

// ---------------------------------------------------------------------------
// bf16 MFMA GEMM body (device fn). BK=64, global_load_lds(16B) staging,
// XOR granule swizzle gk = p ^ (m&7).
// MODE 0: fp32 out, bias b0.  MODE 1: bf16 out, bias b0, *oscale.
// MODE 2: bf16 out, bias b0, * bf16 mulp[m*mul_ld+mul_off+n].
// MODE 3: qkv fused (N=1536): n<512 q (bias b0, *oscale); 512..1023 k
//         (bias b1); n>=1024 V -> vT[b][h][d][s] PLAIN key order.
// ---------------------------------------------------------------------------
template<int FM, int FN, int MODE>
__device__ __forceinline__ void gemm_body(
    int bx, int by, short* As, short* Bs,
    const short* __restrict__ X, int ldx, int xoff,
    const short* __restrict__ W,
    const float* __restrict__ b0p, const float* __restrict__ b1p,
    const float* __restrict__ b2p,
    const short* __restrict__ mulp, int mul_ld, int mul_off,
    void* __restrict__ Cout, short* __restrict__ vtout,
    int ldc, int N, int Kd, float oscale)
{
    constexpr int TM = 32 * FM, TN = 32 * FN;
    const int tid  = threadIdx.x;
    const int wv   = tid >> 6, lane = tid & 63;
    const int ln   = lane & 15, quad = lane >> 4;
    const int wm   = wv >> 1, wn = wv & 1;
    const int m0 = bx * TM, n0 = by * TN;

    floatx4 acc[FM][FN];
#pragma unroll
    for (int i = 0; i < FM; ++i)
#pragma unroll
        for (int j = 0; j < FN; ++j) acc[i][j] = (floatx4){0.f, 0.f, 0.f, 0.f};

    const short* xbase = X + (long)m0 * ldx + xoff;
    const short* wbase = W + (long)n0 * Kd;

    for (int k0 = 0; k0 < Kd; k0 += 64) {
#pragma unroll
        for (int g = tid; g < TM * 8; g += 256) {
            int m = g >> 3, p = g & 7, gk = p ^ (m & 7);
            gl2lds16(xbase + (long)m * ldx + k0 + gk * 8, &As[g * 8]);
        }
#pragma unroll
        for (int g = tid; g < TN * 8; g += 256) {
            int m = g >> 3, p = g & 7, gk = p ^ (m & 7);
            gl2lds16(wbase + (long)m * Kd + k0 + gk * 8, &Bs[g * 8]);
        }
        __syncthreads();
#pragma unroll
        for (int half = 0; half < 2; ++half) {
            short8 afr[FM], bfr[FN];
#pragma unroll
            for (int i = 0; i < FM; ++i) {
                int p = (half * 4 + quad) ^ (ln & 7);
                afr[i] = *(const short8*)&As[(wm * 16 * FM + i * 16 + ln) * 64 + p * 8];
            }
#pragma unroll
            for (int j = 0; j < FN; ++j) {
                int p = (half * 4 + quad) ^ (ln & 7);
                bfr[j] = *(const short8*)&Bs[(wn * 16 * FN + j * 16 + ln) * 64 + p * 8];
            }
#pragma unroll
            for (int i = 0; i < FM; ++i)
#pragma unroll
                for (int j = 0; j < FN; ++j)
                    acc[i][j] = __builtin_amdgcn_mfma_f32_16x16x32_bf16(
                        afr[i], bfr[j], acc[i][j], 0, 0, 0);
        }
        __syncthreads();
    }

#pragma unroll
    for (int j = 0; j < FN; ++j) {
        int n = n0 + wn * 16 * FN + j * 16 + ln;
        if constexpr (MODE == 3) {
            if (n >= 1024) {
                // V third -> vT PLAIN key order, 8B packed stores.
                int hh = (n - 1024) >> 6, dd = (n - 1024) & 63;
                float bv = b2p[n - 1024];
                int mblk = m0 + wm * 16 * FM;             // 64-aligned (FM=4)
                int bidx = mblk >> 11, sblk = mblk & (SS - 1);
                short* dst = vtout + ((long)((bidx * NH + hh) * HD + dd)) * SS + sblk;
#pragma unroll
                for (int i = 0; i < FM; ++i) {
                    unsigned lo = pkbf2(acc[i][j][0] + bv, acc[i][j][1] + bv);
                    unsigned hi = pkbf2(acc[i][j][2] + bv, acc[i][j][3] + bv);
                    *(uint2*)(dst + i * 16 + quad * 4) = make_uint2(lo, hi);
                }
            } else {
                float bv = (n < 512) ? b0p[n] : b1p[n - 512];
                float sc = (n < 512) ? oscale : 1.f;
#pragma unroll
                for (int i = 0; i < FM; ++i) {
#pragma unroll
                    for (int r = 0; r < 4; ++r) {
                        int m = m0 + wm * 16 * FM + i * 16 + quad * 4 + r;
                        float val = (acc[i][j][r] + bv) * sc;
                        ((short*)Cout)[(long)m * ldc + n] = f2bf(val);
                    }
                }
            }
        } else if (n < N) {
            float bv = b0p[n], sc = oscale;
#pragma unroll
            for (int i = 0; i < FM; ++i) {
#pragma unroll
                for (int r = 0; r < 4; ++r) {
                    int m = m0 + wm * 16 * FM + i * 16 + quad * 4 + r;
                    float val = (acc[i][j][r] + bv) * sc;
                    if constexpr (MODE == 2)
                        val *= bf2f(mulp[(long)m * mul_ld + mul_off + n]);
                    if constexpr (MODE == 0)
                        ((float*)Cout)[(long)m * ldc + n] = val;
                    else
                        ((short*)Cout)[(long)m * ldc + n] = f2bf(val);
                }
            }
        }
    }
}

// ---------------------------------------------------------------------------
// mega1: qkv GEMM (768 blocks, FM4/FN4, mode3) || pointwise conv_attn GEMM
// (512 blocks, FM4/FN2, mode2).
// ---------------------------------------------------------------------------
__global__ __launch_bounds__(256) void mega1_kernel(
    const short* __restrict__ hsb, const short* __restrict__ x1c,
    const short* __restrict__ Wqkv_b, const short* __restrict__ pw_b,
    const float* __restrict__ bq, const float* __restrict__ bk,
    const float* __restrict__ bv, const float* __restrict__ sepb,
    short* __restrict__ qkvb, short* __restrict__ vTb,
    short* __restrict__ cabO, float oscale)
{
    __shared__ __align__(16) short As[128 * 64];
    __shared__ __align__(16) short Bs[128 * 64];
    int bid = blockIdx.x;
    if (bid < 768) {          // qkv: grid (64, 12)
        gemm_body<4, 4, 3>(bid & 63, bid >> 6, As, Bs,
            hsb, HIDD, 0, Wqkv_b, bq, bk, bv, nullptr, 0, 0,
            qkvb, vTb, 1536, 1536, AD, oscale);
    } else {                  // pointwise: grid (64, 8)
        int id = bid - 768;
        gemm_body<4, 2, 2>(id & 63, id >> 6, As, Bs,
            x1c, AD, 0, pw_b, sepb, nullptr, nullptr, hsb, HIDD, AD,
            cabO, nullptr, AD, AD, AD, 1.f);
    }
}

// ---------------------------------------------------------------------------
// mega2: col GEMM (512 blocks, FM4/FN2, mode1) || ckl GEMM (256 blocks,
// FM2/FN2, mode0).
// ---------------------------------------------------------------------------
__global__ __launch_bounds__(256) void mega2_kernel(
    const short* __restrict__ hsb, const short* __restrict__ cabO,
    const short* __restrict__ Wco_b, const short* __restrict__ Wck_b,
    const float* __restrict__ bco, const float* __restrict__ bck,
    short* __restrict__ x1c, float* __restrict__ ckl)
{
    __shared__ __align__(16) short As[128 * 64];
    __shared__ __align__(16) short Bs[128 * 64];
    int bid = blockIdx.x;
    if (bid < 512) {          // col: grid (64, 8)
        gemm_body<4, 2, 1>(bid & 63, bid >> 6, As, Bs,
            hsb, HIDD, AD, Wco_b, bco, nullptr, nullptr, nullptr, 0, 0,
            x1c, nullptr, AD, AD, AD, 1.f);
    } else {                  // ckl: grid (128, 2)
        int id = bid - 512;
        gemm_body<2, 2, 0>(id & 127, id >> 7, As, Bs,
            cabO, AD, 0, Wck_b, bck, nullptr, nullptr, nullptr, 0, 0,
            ckl, nullptr, NH * KW, NH * KW, AD, 1.f);
    }
}

// ---------------------------------------------------------------------------
// tail kernel: flash attention (8 waves, 256 q-rows/block, blocks [0,256))
// || convout (blocks [256, 2304), 512 thr each). Disjoint outputs:
// flash -> out[:, :512], convout -> out[:, 512:].
//
// Flash v9 = v8 ring/vmcnt structure at 8 waves: staging is 1 gl2lds per
// thread per buffer (512 granules, 512 threads), 2 loads/phase, counted
// vmcnt(2) (retires phase t-1's pair; 2-phase prefetch depth). K/V L2
// traffic halves vs v8 (one block per (qt,h,b) covers 256 q-rows).
// ---------------------------------------------------------------------------
__global__ __launch_bounds__(512) void tail_kernel(
    const short* __restrict__ qkv, const short* __restrict__ vT,
    const short* __restrict__ colb, const float* __restrict__ cklp,
    float* __restrict__ out)
{
    __shared__ __align__(16) short Kb[3][4096];   // [key][d] ring (swizzled)
    __shared__ __align__(16) short Vb[3][4096];   // [d][key] ring (swizzled)
    __shared__ float ls[8][32];                   // per-wave 1/l broadcast

    const int bid = blockIdx.x;
    const int tid = threadIdx.x;

    if (bid >= 256) {
        // ================= convout branch =================
        int idx = (bid - 256) * 512 + tid;      // over MTOK*AD/4
        int d4  = (idx & 127) * 4;
        int tok = idx >> 7;
        int s   = tok & (SS - 1);
        int b   = tok >> 11;
        int h   = d4 >> 6;
        const float* lg = cklp + (long)tok * (NH * KW) + h * KW;
        float wv[KW];
        float mx = -1e30f;
#pragma unroll
        for (int i = 0; i < KW; ++i) { wv[i] = lg[i]; mx = fmaxf(mx, wv[i]); }
        float sum = 0.f;
#pragma unroll
        for (int i = 0; i < KW; ++i) { wv[i] = __expf(wv[i] - mx); sum += wv[i]; }
        float inv = 1.f / sum;
        float a0 = 0.f, a1 = 0.f, a2 = 0.f, a3 = 0.f;
        const short* cbase = colb + (long)(b * SS) * AD + d4;
#pragma unroll
        for (int kk = 0; kk < KW; ++kk) {
            int ss2 = s + kk - KW / 2;
            if (ss2 >= 0 && ss2 < SS) {
                uint2 cv = *(const uint2*)(cbase + (long)ss2 * AD);
                float w = wv[kk];
                a0 += w * bf2f((short)(cv.x & 0xFFFF));
                a1 += w * bf2f((short)(cv.x >> 16));
                a2 += w * bf2f((short)(cv.y & 0xFFFF));
                a3 += w * bf2f((short)(cv.y >> 16));
            }
        }
        *(float4*)&out[(long)tok * HIDD + AD + d4] =
            make_float4(a0 * inv, a1 * inv, a2 * inv, a3 * inv);
        return;
    }

    // ================= flash branch =================
    const int qt = bid & 7, h = (bid >> 3) & 7, b = bid >> 6;
    const int w    = tid >> 6;        // wave 0..7
    const int lane = tid & 63;
    const int l5   = lane & 31;
    const int hh   = lane >> 5;

    const int  q0 = qt * 256 + w * 32;            // 32 q-rows per wave
    const long rowbase = (long)b * SS;

    // Q resident in regs: lane holds Q[q0+l5][ d = i*16 + hh*8 + 0..7 ]
    short8 qf[4];
    {
        const short* qrow = qkv + (rowbase + q0 + l5) * 1536 + h * HD;
#pragma unroll
        for (int i = 0; i < 4; ++i)
            qf[i] = *(const short8*)(qrow + i * 16 + hh * 8);
    }

    floatx16 acc0, acc1;          // ctx, d 0..31 / 32..63
    floatx16 Z;                   // persistent zero C-in for QK^T
#pragma unroll
    for (int r = 0; r < 16; ++r) { acc0[r] = 0.f; acc1[r] = 0.f; Z[r] = 0.f; }
    float l_i = 0.f;

    // staging: thread handles granule g = tid (512 granules per 64x64 tile)
    const int m1 = tid >> 3, gk1 = (tid & 7) ^ (m1 & 7);
    const short* kbase  = qkv + 512 + rowbase * 1536 + h * HD;
    const short* vtbase = vT + ((long)(b * NH + h) * HD) * SS;
    const short* sk0 = kbase  + (long)m1 * 1536 + gk1 * 8;
    const short* sv0 = vtbase + (long)m1 * SS   + gk1 * 8;

    auto STAGE_K = [&](int slot, bool adv) {
        gl2lds16(sk0, &Kb[slot][tid * 8]);
        if (adv) sk0 += 64 * 1536;
    };
    auto STAGE_V = [&](int slot) {
        gl2lds16(sv0, &Vb[slot][tid * 8]);
        sv0 += 64;
    };

    // ---- S^T = K Q^T (8 MFMA, C-in = Z on first d-slice) ----
    auto qkt = [&](const short* KB, floatx16& S0, floatx16& S1) {
        {
            int p = hh ^ (l5 & 7);
            short8 k0 = *(const short8*)&KB[l5 * 64 + p * 8];
            short8 k1 = *(const short8*)&KB[(32 + l5) * 64 + p * 8];
            S0 = __builtin_amdgcn_mfma_f32_32x32x16_bf16(k0, qf[0], Z, 0, 0, 0);
            S1 = __builtin_amdgcn_mfma_f32_32x32x16_bf16(k1, qf[0], Z, 0, 0, 0);
        }
#pragma unroll
        for (int i = 1; i < 4; ++i) {               // d-slice 16i..16i+15
            int p = (2 * i + hh) ^ (l5 & 7);
            short8 k0 = *(const short8*)&KB[l5 * 64 + p * 8];
            short8 k1 = *(const short8*)&KB[(32 + l5) * 64 + p * 8];
            S0 = __builtin_amdgcn_mfma_f32_32x32x16_bf16(k0, qf[i], S0, 0, 0, 0);
            S1 = __builtin_amdgcn_mfma_f32_32x32x16_bf16(k1, qf[i], S1, 0, 0, 0);
        }
    };

    // ---- exp2 + partial l + pack P into PV A-frags (regs only) ----
    auto smax = [&](const floatx16& S0, const floatx16& S1, short8* pf) {
        float pe0[16], pe1[16];
#pragma unroll
        for (int r = 0; r < 16; ++r) {
            pe0[r] = exp2_raw(S0[r]);
            pe1[r] = exp2_raw(S1[r]);
        }
        float s = 0.f;
#pragma unroll
        for (int r = 0; r < 16; ++r) s += pe0[r] + pe1[r];
        l_i += s;
        // reg r of tile t = key 32t + (r&3) + 8*(r>>2) + 4*hh; swap quad-pair
        // words across lane halves -> frag = plain keys 16u+8hh+0..7.
#pragma unroll
        for (int t = 0; t < 2; ++t) {
            const float* pe = t ? pe1 : pe0;
#pragma unroll
            for (int u = 0; u < 2; ++u) {
                unsigned a0 = pkbf2(pe[8 * u + 0], pe[8 * u + 1]);
                unsigned a1 = pkbf2(pe[8 * u + 2], pe[8 * u + 3]);
                unsigned b0 = pkbf2(pe[8 * u + 4], pe[8 * u + 5]);
                unsigned b1 = pkbf2(pe[8 * u + 6], pe[8 * u + 7]);
                asm("v_permlane32_swap_b32 %0, %1" : "+v"(a0), "+v"(b0));
                asm("v_permlane32_swap_b32 %0, %1" : "+v"(a1), "+v"(b1));
                union { uint4 u4; short8 s8; } cv;
                cv.u4 = make_uint4(a0, a1, b0, b1);
                pf[t * 2 + u] = cv.s8;
            }
        }
    };

    // ---- ctx += P V (8 MFMA; P frags in regs) ----
    auto pv = [&](const short* VB, const short8* pf) {
#pragma unroll
        for (int s = 0; s < 4; ++s) {               // key-slice 16s..16s+15
            int p = (2 * s + hh) ^ (l5 & 7);
            short8 v0 = *(const short8*)&VB[l5 * 64 + p * 8];
            short8 v1 = *(const short8*)&VB[(32 + l5) * 64 + p * 8];
            acc0 = __builtin_amdgcn_mfma_f32_32x32x16_bf16(pf[s], v0, acc0, 0, 0, 0);
            acc1 = __builtin_amdgcn_mfma_f32_32x32x16_bf16(pf[s], v1, acc1, 0, 0, 0);
        }
    };

    short8 pfA[4], pfB[4];

    // pre-prologue: K(0)->slot0, K(1)->slot1, V(0)->slot0; full drain
    STAGE_K(0, true);
    STAGE_K(1, true);
    STAGE_V(0);
    asm volatile("s_waitcnt vmcnt(0)" ::: "memory");
    __builtin_amdgcn_s_barrier();
    asm volatile("" ::: "memory");

    // phase 0: qkt(0) only; stage K(2)->slot2, V(1)->slot1
    {
        STAGE_K(2, true);
        STAGE_V(1);
        floatx16 S0, S1;
        qkt(Kb[0], S0, S1);
        smax(S0, S1, pfA);
        asm volatile("s_waitcnt vmcnt(2)" ::: "memory");
        __builtin_amdgcn_s_barrier();
        asm volatile("" ::: "memory");
    }

    // phases t = 6g+1 .. 6g+6, g = 0..4 (t = 1..30)
#define PHASE(KS, VPS, KST, VST, KADV, PIN, POUT)                      \
    {                                                                  \
        STAGE_K(KST, KADV);                                            \
        STAGE_V(VST);                                                  \
        floatx16 S0, S1;                                               \
        __builtin_amdgcn_s_setprio(1);                                 \
        qkt(Kb[KS], S0, S1);                                           \
        pv(Vb[VPS], PIN);                                              \
        __builtin_amdgcn_s_setprio(0);                                 \
        smax(S0, S1, POUT);                                            \
        asm volatile("s_waitcnt vmcnt(2)" ::: "memory");               \
        __builtin_amdgcn_s_barrier();                                  \
        asm volatile("" ::: "memory");                                 \
    }

    for (int g = 0; g < 5; ++g) {
        bool notlast = (g < 4);
        PHASE(1, 0, 0, 2, true,    pfA, pfB);   // t = 6g+1
        PHASE(2, 1, 1, 0, true,    pfB, pfA);   // t = 6g+2
        PHASE(0, 2, 2, 1, true,    pfA, pfB);   // t = 6g+3
        PHASE(1, 0, 0, 2, true,    pfB, pfA);   // t = 6g+4
        PHASE(2, 1, 1, 0, notlast, pfA, pfB);   // t = 6g+5 (t=29: no adv)
        PHASE(0, 2, 2, 1, notlast, pfB, pfA);   // t = 6g+6 (t=30: re-issue K31)
    }
#undef PHASE

    // phase 31: no stages; full drain (retires V(31) staged at t=30)
    {
        floatx16 S0, S1;
        __builtin_amdgcn_s_setprio(1);
        qkt(Kb[1], S0, S1);       // K(31) in slot 31%3=1 (staged t=29)
        pv(Vb[0], pfA);           // V(30) in slot 30%3=0 (staged t=29)
        __builtin_amdgcn_s_setprio(0);
        smax(S0, S1, pfB);
        asm volatile("s_waitcnt vmcnt(0)" ::: "memory");
        __builtin_amdgcn_s_barrier();
        asm volatile("" ::: "memory");
    }
    // final PV(31): V(31) staged t=30 into slot (30+1)%3=1
    pv(Vb[1], pfB);

    // l: halves hold complementary keys of the same q-row
    l_i += __shfl_xor(l_i, 32);
    ls[w][l5] = 1.f / l_i;          // lanes l5 and l5+32 write same value
    // wave-synchronous LDS (same-wave DS FIFO) - no barrier needed
    float4 lv[4];
#pragma unroll
    for (int g = 0; g < 4; ++g)
        lv[g] = *(const float4*)&ls[w][8 * g + 4 * hh];

    // acc layout: col = l5 = d-offset, row(reg r) = (r&3) + 8*(r>>2) + 4*hh
#pragma unroll
    for (int r = 0; r < 16; ++r) {
        int g = r >> 2, j = r & 3;
        int qr = j + 8 * g + 4 * hh;
        float iv = lv[g][j];
        float* orow = out + (rowbase + q0 + qr) * HIDD + h * HD;
        orow[l5]      = acc0[r] * iv;
        orow[32 + l5] = acc1[r] * iv;
    }
}

// ---------------------------------------------------------------------------
extern "C" void kernel_launch(void* const* d_in, const int* in_sizes, int n_in,
                              void* d_out, int out_size, void* d_ws, size_t ws_size,
                              hipStream_t stream)
{
    const float* hs   = (const float*)d_in[0];
    const float* Wq   = (const float*)d_in[1];
    const float* bq   = (const float*)d_in[2];
    const float* Wk   = (const float*)d_in[3];
    const float* bk   = (const float*)d_in[4];
    const float* Wv   = (const float*)d_in[5];
    const float* bv   = (const float*)d_in[6];
    const float* dw   = (const float*)d_in[7];
    const float* pw   = (const float*)d_in[8];
    const float* sepb = (const float*)d_in[9];
    const float* Wck  = (const float*)d_in[10];
    const float* bck  = (const float*)d_in[11];
    const float* Wco  = (const float*)d_in[12];
    const float* bco  = (const float*)d_in[13];
    float* out = (float*)d_out;

    // workspace (bf16 shorts unless noted)
    short* hsb  = (short*)d_ws;                       // MTOK x 1024
    short* x1c  = hsb + (long)MTOK * HIDD;            // MTOK x 512 (x1, then col)
    short* qkvb = x1c + (long)MTOK * AD;              // MTOK x 1536
    short* vTb  = qkvb + (long)MTOK * 1536;           // [b][h][d][s] MTOK*512
    float* ckl  = (float*)(vTb + (long)MTOK * AD);    // MTOK x 72 fp32 logits
    short* wb   = (short*)(ckl + (long)MTOK * (NH * KW));
    short* pw_b   = wb;
    short* Wco_b  = wb + 1L * WSZ;
    short* Wqkv_b = wb + 2L * WSZ;                    // [Wq;Wk;Wv] 1536 x 512
    short* Wck_b  = wb + 5L * WSZ;                    // 128 x 512 (padded)
    // conv_attn scratch lives in d_out (dead until the tail kernel, which
    // overwrites every element of out).
    short* cabO   = (short*)d_out;                    // MTOK x 512 bf16

    const float QSCALE = 0.18033688011112042f;        // log2(e)/8

    // L1: fused conversions + depthwise conv (mutually independent branches)
    prep_kernel<<<6816, 256, 0, stream>>>(
        hs, pw, Wco, Wq, Wk, Wv, Wck, dw, hsb, wb, x1c);
    // L2: qkv GEMM || pointwise conv_attn GEMM
    mega1_kernel<<<1280, 256, 0, stream>>>(
        hsb, x1c, Wqkv_b, pw_b, bq, bk, bv, sepb, qkvb, vTb, cabO, QSCALE);
    // L3: col GEMM || ckl logits GEMM
    mega2_kernel<<<768, 256, 0, stream>>>(
        hsb, cabO, Wco_b, Wck_b, bco, bck, x1c, ckl);
    // L4: flash attention (256 blocks) || convout (2048 blocks)
    tail_kernel<<<2304, 512, 0, stream>>>(qkvb, vTb, x1c, ckl, out);

    (void)in_sizes; (void)n_in; (void)out_size; (void)ws_size;
}

// Round 9
// 211.593 us; speedup vs baseline: 1.0549x; 1.0549x over previous
//
#include <hip/hip_runtime.h>
#include <hip/hip_bf16.h>

// Problem constants (ConvBertSelfAttention): B=4, S=2048, H=8, D=64, K=9
#define NH   8
#define HD   64
#define KW   9
#define AD   512      // H*D
#define HIDD 1024     // 2*A
#define BB   4
#define SS   2048
#define MTOK (BB*SS)  // 8192 tokens
#define WSZ  262144   // 512*512 weight elements

typedef __attribute__((ext_vector_type(8))) short short8;    // 8 bf16 (4 VGPRs)
typedef __attribute__((ext_vector_type(4))) float floatx4;   // 16x16 MFMA C/D
typedef __attribute__((ext_vector_type(16))) float floatx16; // 32x32 MFMA C/D

__device__ __forceinline__ short f2bf(float f) {
    unsigned u = __float_as_uint(f);
    u = (u + 0x7FFFu + ((u >> 16) & 1u)) >> 16;
    return (short)u;
}
__device__ __forceinline__ float bf2f(short s) {
    return __uint_as_float(((unsigned)(unsigned short)s) << 16);
}
// raw v_exp_f32 (2^x)
__device__ __forceinline__ float exp2_raw(float x) {
    return __builtin_amdgcn_exp2f(x);
}
// pack two floats to two bf16: a -> low16, b -> high16 (RNE, 1 instr)
__device__ __forceinline__ unsigned pkbf2(float a, float b) {
    unsigned d;
    asm("v_cvt_pk_bf16_f32 %0, %1, %2" : "=v"(d) : "v"(a), "v"(b));
    return d;
}
// async global->LDS, 16 B per lane; LDS dest = wave-uniform base + lane*16
__device__ __forceinline__ void gl2lds16(const short* g, short* l) {
    __builtin_amdgcn_global_load_lds(
        (const __attribute__((address_space(1))) void*)g,
        (__attribute__((address_space(3))) void*)l, 16, 0, 0);
}

// ---------------------------------------------------------------------------
// prep kernel: fused {hs fp32->bf16 | weights fp32->bf16 | depthwise conv}.
// Block ranges: [0,4096) cvt_hs, [4096,4768) cvt_w, [4768,6816) dwconv.
// ---------------------------------------------------------------------------
__global__ __launch_bounds__(256) void prep_kernel(
    const float* __restrict__ hs,
    const float* __restrict__ pw, const float* __restrict__ Wco,
    const float* __restrict__ Wq, const float* __restrict__ Wk,
    const float* __restrict__ Wv, const float* __restrict__ Wck,
    const float* __restrict__ dw,
    short* __restrict__ hsb, short* __restrict__ wb, short* __restrict__ x1)
{
    __shared__ float wl[KW * AD];            // 18 KB (dwconv branch only)
    const int bid = blockIdx.x, tid = threadIdx.x;

    if (bid < 4096) {
        // ---- cvt_hs: MTOK x 1024 fp32 -> bf16, 8 elem/thread ----
        int idx = bid * 256 + tid;
        const float* s = hs + (long)idx * 8;
        float4 a = *(const float4*)s, c = *(const float4*)(s + 4);
        short8 o;
        o[0]=f2bf(a.x); o[1]=f2bf(a.y); o[2]=f2bf(a.z); o[3]=f2bf(a.w);
        o[4]=f2bf(c.x); o[5]=f2bf(c.y); o[6]=f2bf(c.z); o[7]=f2bf(c.w);
        *(short8*)(hsb + (long)idx * 8) = o;
    } else if (bid < 4768) {
        // ---- cvt_w: [pw][Wco][Wq][Wk][Wv][Wck padded 128x512] ----
        int idx = (bid - 4096) * 256 + tid;  // [0, 172032)
        int e0 = idx * 8;
        short8 o;
        if (e0 < 5 * WSZ) {
            int w = e0 >> 18, off = e0 & (WSZ - 1);
            const float* src = (w == 0) ? pw : (w == 1) ? Wco : (w == 2) ? Wq
                             : (w == 3) ? Wk : Wv;
            float4 a = *(const float4*)(src + off), c = *(const float4*)(src + off + 4);
            o[0]=f2bf(a.x); o[1]=f2bf(a.y); o[2]=f2bf(a.z); o[3]=f2bf(a.w);
            o[4]=f2bf(c.x); o[5]=f2bf(c.y); o[6]=f2bf(c.z); o[7]=f2bf(c.w);
        } else {
            int off = e0 - 5 * WSZ;          // 0 .. 65535 over 128x512
            int row = off >> 9, col = off & 511;
            if (row < NH * KW) {
                const float* src = Wck + row * AD + col;
                float4 a = *(const float4*)src, c = *(const float4*)(src + 4);
                o[0]=f2bf(a.x); o[1]=f2bf(a.y); o[2]=f2bf(a.z); o[3]=f2bf(a.w);
                o[4]=f2bf(c.x); o[5]=f2bf(c.y); o[6]=f2bf(c.z); o[7]=f2bf(c.w);
            } else {
                for (int i = 0; i < 8; ++i) o[i] = 0;
            }
        }
        *(short8*)(wb + e0) = o;
    } else {
        // ---- dwconv: 8 ch/thread, fp32 inputs, dw staged transposed ----
        for (int t = tid; t < KW * AD; t += 256) {
            int c = t / KW, k = t - c * KW;  // dw linear = [c][k]
            wl[k * AD + c] = dw[t];
        }
        __syncthreads();
        int idx = (bid - 4768) * 256 + tid;  // over MTOK*AD/8
        int c8  = (idx & 63) * 8;
        int tok = idx >> 6;
        int s   = tok & (SS - 1);
        int b   = tok >> 11;
        const float* base = hs + (long)(b * SS) * HIDD + AD + c8;
        float acc[8];
#pragma unroll
        for (int i = 0; i < 8; ++i) acc[i] = 0.f;
#pragma unroll
        for (int kk = 0; kk < KW; ++kk) {
            int ss2 = s + kk - KW / 2;
            if (ss2 >= 0 && ss2 < SS) {
                const float* hp = base + (long)ss2 * HIDD;
                float4 h0 = *(const float4*)hp;
                float4 h1 = *(const float4*)(hp + 4);
                float4 w0 = *(const float4*)(wl + kk * AD + c8);
                float4 w1 = *(const float4*)(wl + kk * AD + c8 + 4);
                acc[0] += w0.x * h0.x; acc[1] += w0.y * h0.y;
                acc[2] += w0.z * h0.z; acc[3] += w0.w * h0.w;
                acc[4] += w1.x * h1.x; acc[5] += w1.y * h1.y;
                acc[6] += w1.z * h1.z; acc[7] += w1.w * h1.w;
            }
        }
        short8 o;
#pragma unroll
        for (int i = 0; i < 8; ++i) o[i] = f2bf(acc[i]);
        *(short8*)(x1 + (long)tok * AD + c8) = o;
    }
}

// ---------------------------------------------------------------------------
// bf16 MFMA GEMM body (device fn). BK=64, global_load_lds(16B) staging,
// XOR granule swizzle gk = p ^ (m&7).
// MODE 0: fp32 out, bias b0.  MODE 1: bf16 out, bias b0, *oscale.
// MODE 2: bf16 out, bias b0, * bf16 mulp[m*mul_ld+mul_off+n].
// MODE 3: qkv fused (N=1536): n<512 q (bias b0, *oscale); 512..1023 k
//         (bias b1); n>=1024 V -> vT[b][h][d][s] PLAIN key order.
// ---------------------------------------------------------------------------
template<int FM, int FN, int MODE>
__device__ __forceinline__ void gemm_body(
    int bx, int by, short* As, short* Bs,
    const short* __restrict__ X, int ldx, int xoff,
    const short* __restrict__ W,
    const float* __restrict__ b0p, const float* __restrict__ b1p,
    const float* __restrict__ b2p,
    const short* __restrict__ mulp, int mul_ld, int mul_off,
    void* __restrict__ Cout, short* __restrict__ vtout,
    int ldc, int N, int Kd, float oscale)
{
    constexpr int TM = 32 * FM, TN = 32 * FN;
    const int tid  = threadIdx.x;
    const int wv   = tid >> 6, lane = tid & 63;
    const int ln   = lane & 15, quad = lane >> 4;
    const int wm   = wv >> 1, wn = wv & 1;
    const int m0 = bx * TM, n0 = by * TN;

    floatx4 acc[FM][FN];
#pragma unroll
    for (int i = 0; i < FM; ++i)
#pragma unroll
        for (int j = 0; j < FN; ++j) acc[i][j] = (floatx4){0.f, 0.f, 0.f, 0.f};

    const short* xbase = X + (long)m0 * ldx + xoff;
    const short* wbase = W + (long)n0 * Kd;

    for (int k0 = 0; k0 < Kd; k0 += 64) {
#pragma unroll
        for (int g = tid; g < TM * 8; g += 256) {
            int m = g >> 3, p = g & 7, gk = p ^ (m & 7);
            gl2lds16(xbase + (long)m * ldx + k0 + gk * 8, &As[g * 8]);
        }
#pragma unroll
        for (int g = tid; g < TN * 8; g += 256) {
            int m = g >> 3, p = g & 7, gk = p ^ (m & 7);
            gl2lds16(wbase + (long)m * Kd + k0 + gk * 8, &Bs[g * 8]);
        }
        __syncthreads();
#pragma unroll
        for (int half = 0; half < 2; ++half) {
            short8 afr[FM], bfr[FN];
#pragma unroll
            for (int i = 0; i < FM; ++i) {
                int p = (half * 4 + quad) ^ (ln & 7);
                afr[i] = *(const short8*)&As[(wm * 16 * FM + i * 16 + ln) * 64 + p * 8];
            }
#pragma unroll
            for (int j = 0; j < FN; ++j) {
                int p = (half * 4 + quad) ^ (ln & 7);
                bfr[j] = *(const short8*)&Bs[(wn * 16 * FN + j * 16 + ln) * 64 + p * 8];
            }
#pragma unroll
            for (int i = 0; i < FM; ++i)
#pragma unroll
                for (int j = 0; j < FN; ++j)
                    acc[i][j] = __builtin_amdgcn_mfma_f32_16x16x32_bf16(
                        afr[i], bfr[j], acc[i][j], 0, 0, 0);
        }
        __syncthreads();
    }

#pragma unroll
    for (int j = 0; j < FN; ++j) {
        int n = n0 + wn * 16 * FN + j * 16 + ln;
        if constexpr (MODE == 3) {
            if (n >= 1024) {
                // V third -> vT PLAIN key order, 8B packed stores.
                int hh = (n - 1024) >> 6, dd = (n - 1024) & 63;
                float bv = b2p[n - 1024];
                int mblk = m0 + wm * 16 * FM;             // 64-aligned (FM=4)
                int bidx = mblk >> 11, sblk = mblk & (SS - 1);
                short* dst = vtout + ((long)((bidx * NH + hh) * HD + dd)) * SS + sblk;
#pragma unroll
                for (int i = 0; i < FM; ++i) {
                    unsigned lo = pkbf2(acc[i][j][0] + bv, acc[i][j][1] + bv);
                    unsigned hi = pkbf2(acc[i][j][2] + bv, acc[i][j][3] + bv);
                    *(uint2*)(dst + i * 16 + quad * 4) = make_uint2(lo, hi);
                }
            } else {
                float bv = (n < 512) ? b0p[n] : b1p[n - 512];
                float sc = (n < 512) ? oscale : 1.f;
#pragma unroll
                for (int i = 0; i < FM; ++i) {
#pragma unroll
                    for (int r = 0; r < 4; ++r) {
                        int m = m0 + wm * 16 * FM + i * 16 + quad * 4 + r;
                        float val = (acc[i][j][r] + bv) * sc;
                        ((short*)Cout)[(long)m * ldc + n] = f2bf(val);
                    }
                }
            }
        } else if (n < N) {
            float bv = b0p[n], sc = oscale;
#pragma unroll
            for (int i = 0; i < FM; ++i) {
#pragma unroll
                for (int r = 0; r < 4; ++r) {
                    int m = m0 + wm * 16 * FM + i * 16 + quad * 4 + r;
                    float val = (acc[i][j][r] + bv) * sc;
                    if constexpr (MODE == 2)
                        val *= bf2f(mulp[(long)m * mul_ld + mul_off + n]);
                    if constexpr (MODE == 0)
                        ((float*)Cout)[(long)m * ldc + n] = val;
                    else
                        ((short*)Cout)[(long)m * ldc + n] = f2bf(val);
                }
            }
        }
    }
}

// ---------------------------------------------------------------------------
// mega1: qkv GEMM (768 blocks, FM4/FN4, mode3) || pointwise conv_attn GEMM
// (256 blocks, FM4/FN4 = 128x128 tile, mode2 -> cabO strided in d_out).
// ---------------------------------------------------------------------------
__global__ __launch_bounds__(256) void mega1_kernel(
    const short* __restrict__ hsb, const short* __restrict__ x1c,
    const short* __restrict__ Wqkv_b, const short* __restrict__ pw_b,
    const float* __restrict__ bq, const float* __restrict__ bk,
    const float* __restrict__ bv, const float* __restrict__ sepb,
    short* __restrict__ qkvb, short* __restrict__ vTb,
    short* __restrict__ cabO, float oscale)
{
    __shared__ __align__(16) short As[128 * 64];
    __shared__ __align__(16) short Bs[128 * 64];
    int bid = blockIdx.x;
    if (bid < 768) {          // qkv: grid (64, 12)
        gemm_body<4, 4, 3>(bid & 63, bid >> 6, As, Bs,
            hsb, HIDD, 0, Wqkv_b, bq, bk, bv, nullptr, 0, 0,
            qkvb, vTb, 1536, 1536, AD, oscale);
    } else {                  // pointwise: grid (64, 4), ldc = 2048 (strided)
        int id = bid - 768;
        gemm_body<4, 4, 2>(id & 63, id >> 6, As, Bs,
            x1c, AD, 0, pw_b, sepb, nullptr, nullptr, hsb, HIDD, AD,
            cabO, nullptr, 2048, AD, AD, 1.f);
    }
}

// ---------------------------------------------------------------------------
// mega3: flash attention v8 (blocks [0,512), 4 waves, 128 q-rows) ||
// col GEMM (blocks [512,768), FM4/FN4, mode1) || ckl GEMM (blocks
// [768,1024), FM2/FN2, mode0, A = cabO strided ldx=2048).
// All three depend only on mega1: flash reads qkvb/vTb; col reads hsb,
// writes x1c (x1 dead after mega1); ckl reads cabO (d_out cols [512:),
// disjoint from flash's out cols [0,512)).
// ---------------------------------------------------------------------------
__global__ __launch_bounds__(256) void mega3_kernel(
    const short* __restrict__ qkv, const short* __restrict__ vT,
    const short* __restrict__ hsb, const short* __restrict__ cabO,
    const short* __restrict__ Wco_b, const short* __restrict__ Wck_b,
    const float* __restrict__ bco, const float* __restrict__ bck,
    short* __restrict__ x1c, float* __restrict__ cklp,
    float* __restrict__ out)
{
    __shared__ __align__(16) char smem[49664];
    const int bid = blockIdx.x;
    const int tid = threadIdx.x;

    if (bid >= 512) {
        short* As = (short*)smem;
        short* Bs = (short*)smem + 128 * 64;
        if (bid < 768) {      // col: grid (64, 4)
            int id = bid - 512;
            gemm_body<4, 4, 1>(id & 63, id >> 6, As, Bs,
                hsb, HIDD, AD, Wco_b, bco, nullptr, nullptr, nullptr, 0, 0,
                x1c, nullptr, AD, AD, AD, 1.f);
        } else {              // ckl: grid (128, 2), A strided ldx=2048
            int id = bid - 768;
            gemm_body<2, 2, 0>(id & 127, id >> 7, As, Bs,
                cabO, 2048, 0, Wck_b, bck, nullptr, nullptr, nullptr, 0, 0,
                cklp, nullptr, NH * KW, NH * KW, AD, 1.f);
        }
        return;
    }

    // ================= flash v8 branch (identical to round-7 kernel) ======
    short* const KbB = (short*)smem;                 // 3 slots x 4096 shorts
    short* const VbB = (short*)smem + 3 * 4096;      // 3 slots x 4096 shorts
    float* const ls  = (float*)(smem + 49152);       // [4][32]

    const int qt = bid & 15, h = (bid >> 4) & 7, b = bid >> 7;
    const int w    = tid >> 6;        // wave 0..3
    const int lane = tid & 63;
    const int l5   = lane & 31;
    const int hh   = lane >> 5;

    const int  q0 = qt * 128 + w * 32;            // 32 q-rows per wave
    const long rowbase = (long)b * SS;

    // Q resident in regs: lane holds Q[q0+l5][ d = i*16 + hh*8 + 0..7 ]
    short8 qf[4];
    {
        const short* qrow = qkv + (rowbase + q0 + l5) * 1536 + h * HD;
#pragma unroll
        for (int i = 0; i < 4; ++i)
            qf[i] = *(const short8*)(qrow + i * 16 + hh * 8);
    }

    floatx16 acc0, acc1;          // ctx, d 0..31 / 32..63
    floatx16 Z;                   // persistent zero C-in for QK^T
#pragma unroll
    for (int r = 0; r < 16; ++r) { acc0[r] = 0.f; acc1[r] = 0.f; Z[r] = 0.f; }
    float l_i = 0.f;

    // hoisted staging pointers: thread handles granules g1=tid, g2=tid+256
    const int m1 = tid >> 3,  gk1 = (tid & 7) ^ (m1 & 7);
    const int g2 = 256 + tid;
    const int m2 = g2 >> 3,   gk2 = (g2 & 7) ^ (m2 & 7);
    const short* kbase  = qkv + 512 + rowbase * 1536 + h * HD;
    const short* vtbase = vT + ((long)(b * NH + h) * HD) * SS;
    const short* sk0 = kbase  + (long)m1 * 1536 + gk1 * 8;
    const short* sk1 = kbase  + (long)m2 * 1536 + gk2 * 8;
    const short* sv0 = vtbase + (long)m1 * SS   + gk1 * 8;
    const short* sv1 = vtbase + (long)m2 * SS   + gk2 * 8;

    auto STAGE_K = [&](int slot, bool adv) {
        gl2lds16(sk0, KbB + slot * 4096 + tid * 8);
        gl2lds16(sk1, KbB + slot * 4096 + g2 * 8);
        if (adv) { sk0 += 64 * 1536; sk1 += 64 * 1536; }
    };
    auto STAGE_V = [&](int slot) {
        gl2lds16(sv0, VbB + slot * 4096 + tid * 8);
        gl2lds16(sv1, VbB + slot * 4096 + g2 * 8);
        sv0 += 64; sv1 += 64;
    };

    // ---- S^T = K Q^T (8 MFMA, C-in = Z on first d-slice) ----
    auto qkt = [&](const short* KB, floatx16& S0, floatx16& S1) {
        {
            int p = hh ^ (l5 & 7);
            short8 k0 = *(const short8*)&KB[l5 * 64 + p * 8];
            short8 k1 = *(const short8*)&KB[(32 + l5) * 64 + p * 8];
            S0 = __builtin_amdgcn_mfma_f32_32x32x16_bf16(k0, qf[0], Z, 0, 0, 0);
            S1 = __builtin_amdgcn_mfma_f32_32x32x16_bf16(k1, qf[0], Z, 0, 0, 0);
        }
#pragma unroll
        for (int i = 1; i < 4; ++i) {               // d-slice 16i..16i+15
            int p = (2 * i + hh) ^ (l5 & 7);
            short8 k0 = *(const short8*)&KB[l5 * 64 + p * 8];
            short8 k1 = *(const short8*)&KB[(32 + l5) * 64 + p * 8];
            S0 = __builtin_amdgcn_mfma_f32_32x32x16_bf16(k0, qf[i], S0, 0, 0, 0);
            S1 = __builtin_amdgcn_mfma_f32_32x32x16_bf16(k1, qf[i], S1, 0, 0, 0);
        }
    };

    // ---- exp2 + partial l + pack P into PV A-frags (regs only) ----
    auto smax = [&](const floatx16& S0, const floatx16& S1, short8* pf) {
        float pe0[16], pe1[16];
#pragma unroll
        for (int r = 0; r < 16; ++r) {
            pe0[r] = exp2_raw(S0[r]);
            pe1[r] = exp2_raw(S1[r]);
        }
        float s = 0.f;
#pragma unroll
        for (int r = 0; r < 16; ++r) s += pe0[r] + pe1[r];
        l_i += s;
#pragma unroll
        for (int t = 0; t < 2; ++t) {
            const float* pe = t ? pe1 : pe0;
#pragma unroll
            for (int u = 0; u < 2; ++u) {
                unsigned a0 = pkbf2(pe[8 * u + 0], pe[8 * u + 1]);
                unsigned a1 = pkbf2(pe[8 * u + 2], pe[8 * u + 3]);
                unsigned b0 = pkbf2(pe[8 * u + 4], pe[8 * u + 5]);
                unsigned b1 = pkbf2(pe[8 * u + 6], pe[8 * u + 7]);
                asm("v_permlane32_swap_b32 %0, %1" : "+v"(a0), "+v"(b0));
                asm("v_permlane32_swap_b32 %0, %1" : "+v"(a1), "+v"(b1));
                union { uint4 u4; short8 s8; } cv;
                cv.u4 = make_uint4(a0, a1, b0, b1);
                pf[t * 2 + u] = cv.s8;
            }
        }
    };

    // ---- ctx += P V (8 MFMA; P frags in regs) ----
    auto pv = [&](const short* VB, const short8* pf) {
#pragma unroll
        for (int s = 0; s < 4; ++s) {               // key-slice 16s..16s+15
            int p = (2 * s + hh) ^ (l5 & 7);
            short8 v0 = *(const short8*)&VB[l5 * 64 + p * 8];
            short8 v1 = *(const short8*)&VB[(32 + l5) * 64 + p * 8];
            acc0 = __builtin_amdgcn_mfma_f32_32x32x16_bf16(pf[s], v0, acc0, 0, 0, 0);
            acc1 = __builtin_amdgcn_mfma_f32_32x32x16_bf16(pf[s], v1, acc1, 0, 0, 0);
        }
    };

    short8 pfA[4], pfB[4];

    // pre-prologue: K(0)->slot0, K(1)->slot1, V(0)->slot0; full drain
    STAGE_K(0, true);
    STAGE_K(1, true);
    STAGE_V(0);
    asm volatile("s_waitcnt vmcnt(0)" ::: "memory");
    __builtin_amdgcn_s_barrier();
    asm volatile("" ::: "memory");

    // phase 0: qkt(0) only; stage K(2)->slot2, V(1)->slot1
    {
        STAGE_K(2, true);
        STAGE_V(1);
        floatx16 S0, S1;
        qkt(KbB, S0, S1);
        smax(S0, S1, pfA);
        asm volatile("s_waitcnt vmcnt(4)" ::: "memory");
        __builtin_amdgcn_s_barrier();
        asm volatile("" ::: "memory");
    }

    // phases t = 6g+1 .. 6g+6, g = 0..4 (t = 1..30)
#define PHASE(KS, VPS, KST, VST, KADV, PIN, POUT)                      \
    {                                                                  \
        STAGE_K(KST, KADV);                                            \
        STAGE_V(VST);                                                  \
        floatx16 S0, S1;                                               \
        __builtin_amdgcn_s_setprio(1);                                 \
        qkt(KbB + (KS) * 4096, S0, S1);                                \
        pv(VbB + (VPS) * 4096, PIN);                                   \
        __builtin_amdgcn_s_setprio(0);                                 \
        smax(S0, S1, POUT);                                            \
        asm volatile("s_waitcnt vmcnt(4)" ::: "memory");               \
        __builtin_amdgcn_s_barrier();                                  \
        asm volatile("" ::: "memory");                                 \
    }

    for (int g = 0; g < 5; ++g) {
        bool notlast = (g < 4);
        PHASE(1, 0, 0, 2, true,    pfA, pfB);   // t = 6g+1
        PHASE(2, 1, 1, 0, true,    pfB, pfA);   // t = 6g+2
        PHASE(0, 2, 2, 1, true,    pfA, pfB);   // t = 6g+3
        PHASE(1, 0, 0, 2, true,    pfB, pfA);   // t = 6g+4
        PHASE(2, 1, 1, 0, notlast, pfA, pfB);   // t = 6g+5 (t=29: no adv)
        PHASE(0, 2, 2, 1, notlast, pfB, pfA);   // t = 6g+6 (t=30: re-issue K31)
    }
#undef PHASE

    // phase 31: no stages; full drain (retires V(31) staged at t=30)
    {
        floatx16 S0, S1;
        __builtin_amdgcn_s_setprio(1);
        qkt(KbB + 1 * 4096, S0, S1);  // K(31) in slot 31%3=1 (staged t=29)
        pv(VbB + 0 * 4096, pfA);      // V(30) in slot 30%3=0 (staged t=29)
        __builtin_amdgcn_s_setprio(0);
        smax(S0, S1, pfB);
        asm volatile("s_waitcnt vmcnt(0)" ::: "memory");
        __builtin_amdgcn_s_barrier();
        asm volatile("" ::: "memory");
    }
    // final PV(31): V(31) staged t=30 into slot (30+1)%3=1
    pv(VbB + 1 * 4096, pfB);

    // l: halves hold complementary keys of the same q-row
    l_i += __shfl_xor(l_i, 32);
    ls[w * 32 + l5] = 1.f / l_i;    // lanes l5 and l5+32 write same value
    // wave-synchronous LDS (same-wave DS FIFO) - no barrier needed
    float4 lv[4];
#pragma unroll
    for (int g = 0; g < 4; ++g)
        lv[g] = *(const float4*)&ls[w * 32 + 8 * g + 4 * hh];

    // acc layout: col = l5 = d-offset, row(reg r) = (r&3) + 8*(r>>2) + 4*hh
#pragma unroll
    for (int r = 0; r < 16; ++r) {
        int g = r >> 2, j = r & 3;
        int qr = j + 8 * g + 4 * hh;
        float iv = lv[g][j];
        float* orow = out + (rowbase + q0 + qr) * HIDD + h * HD;
        orow[l5]      = acc0[r] * iv;
        orow[32 + l5] = acc1[r] * iv;
    }
}

// ---------------------------------------------------------------------------
// conv_out, 4 channels/thread: out[b,s,h,d4..d4+3] =
//   sum_k col[b,s+k-4,h*64+d4..] * softmax9(logits[b,s,h,:])[k]
// ---------------------------------------------------------------------------
__global__ __launch_bounds__(256) void convout_kernel(
    const short* __restrict__ col, const float* __restrict__ ckl,
    float* __restrict__ out)
{
    int idx = blockIdx.x * 256 + threadIdx.x;   // over MTOK*AD/4
    int d4  = (idx & 127) * 4;                  // channel quad (0..508)
    int tok = idx >> 7;
    int s   = tok & (SS - 1);
    int b   = tok >> 11;
    int h   = d4 >> 6;
    const float* lg = ckl + (long)tok * (NH * KW) + h * KW;
    float wv[KW];
    float mx = -1e30f;
#pragma unroll
    for (int i = 0; i < KW; ++i) { wv[i] = lg[i]; mx = fmaxf(mx, wv[i]); }
    float sum = 0.f;
#pragma unroll
    for (int i = 0; i < KW; ++i) { wv[i] = __expf(wv[i] - mx); sum += wv[i]; }
    float inv = 1.f / sum;
    float a0 = 0.f, a1 = 0.f, a2 = 0.f, a3 = 0.f;
    const short* cbase = col + (long)(b * SS) * AD + d4;
#pragma unroll
    for (int kk = 0; kk < KW; ++kk) {
        int ss2 = s + kk - KW / 2;
        if (ss2 >= 0 && ss2 < SS) {
            uint2 cv = *(const uint2*)(cbase + (long)ss2 * AD);
            float w = wv[kk];
            a0 += w * bf2f((short)(cv.x & 0xFFFF));
            a1 += w * bf2f((short)(cv.x >> 16));
            a2 += w * bf2f((short)(cv.y & 0xFFFF));
            a3 += w * bf2f((short)(cv.y >> 16));
        }
    }
    *(float4*)&out[(long)tok * HIDD + AD + d4] =
        make_float4(a0 * inv, a1 * inv, a2 * inv, a3 * inv);
}

// ---------------------------------------------------------------------------
extern "C" void kernel_launch(void* const* d_in, const int* in_sizes, int n_in,
                              void* d_out, int out_size, void* d_ws, size_t ws_size,
                              hipStream_t stream)
{
    const float* hs   = (const float*)d_in[0];
    const float* Wq   = (const float*)d_in[1];
    const float* bq   = (const float*)d_in[2];
    const float* Wk   = (const float*)d_in[3];
    const float* bk   = (const float*)d_in[4];
    const float* Wv   = (const float*)d_in[5];
    const float* bv   = (const float*)d_in[6];
    const float* dw   = (const float*)d_in[7];
    const float* pw   = (const float*)d_in[8];
    const float* sepb = (const float*)d_in[9];
    const float* Wck  = (const float*)d_in[10];
    const float* bck  = (const float*)d_in[11];
    const float* Wco  = (const float*)d_in[12];
    const float* bco  = (const float*)d_in[13];
    float* out = (float*)d_out;

    // workspace (bf16 shorts unless noted)
    short* hsb  = (short*)d_ws;                       // MTOK x 1024
    short* x1c  = hsb + (long)MTOK * HIDD;            // MTOK x 512 (x1, then col)
    short* qkvb = x1c + (long)MTOK * AD;              // MTOK x 1536
    short* vTb  = qkvb + (long)MTOK * 1536;           // [b][h][d][s] MTOK*512
    float* ckl  = (float*)(vTb + (long)MTOK * AD);    // MTOK x 72 fp32 logits
    short* wb   = (short*)(ckl + (long)MTOK * (NH * KW));
    short* pw_b   = wb;
    short* Wco_b  = wb + 1L * WSZ;
    short* Wqkv_b = wb + 2L * WSZ;                    // [Wq;Wk;Wv] 1536 x 512
    short* Wck_b  = wb + 5L * WSZ;                    // 128 x 512 (padded)
    // conv_attn scratch: STRIDED into d_out's second-half columns.
    // Element (m,n) lives at ((short*)out)[m*2048 + 1024 + n] -- bytes
    // [2048,3072) of each 4096-B row. Flash (mega3) writes only fp32 cols
    // [0,512) = bytes [0,2048) -> disjoint. convout overwrites the region
    // only in L4, after ckl consumed it in L3.
    short* cabO   = (short*)d_out + 1024;             // ld = 2048 shorts

    const float QSCALE = 0.18033688011112042f;        // log2(e)/8

    // L1: fused conversions + depthwise conv (mutually independent branches)
    prep_kernel<<<6816, 256, 0, stream>>>(
        hs, pw, Wco, Wq, Wk, Wv, Wck, dw, hsb, wb, x1c);
    // L2: qkv GEMM || pointwise conv_attn GEMM (cabO strided, ldc=2048)
    mega1_kernel<<<1024, 256, 0, stream>>>(
        hsb, x1c, Wqkv_b, pw_b, bq, bk, bv, sepb, qkvb, vTb, cabO, QSCALE);
    // L3: flash attention (512) || col GEMM (256) || ckl GEMM (256)
    mega3_kernel<<<1024, 256, 0, stream>>>(
        qkvb, vTb, hsb, cabO, Wco_b, Wck_b, bco, bck, x1c, ckl, out);
    // L4: windowed mix w/ fused softmax9 -> out[..., 512:]
    convout_kernel<<<MTOK * AD / 1024, 256, 0, stream>>>(x1c, ckl, out);

    (void)in_sizes; (void)n_in; (void)out_size; (void)ws_size;
}

// Round 10
// 207.866 us; speedup vs baseline: 1.0738x; 1.0179x over previous
//
#include <hip/hip_runtime.h>
#include <hip/hip_bf16.h>

// Problem constants (ConvBertSelfAttention): B=4, S=2048, H=8, D=64, K=9
#define NH   8
#define HD   64
#define KW   9
#define AD   512      // H*D
#define HIDD 1024     // 2*A
#define BB   4
#define SS   2048
#define MTOK (BB*SS)  // 8192 tokens
#define WSZ  262144   // 512*512 weight elements

typedef __attribute__((ext_vector_type(8))) short short8;    // 8 bf16 (4 VGPRs)
typedef __attribute__((ext_vector_type(4))) float floatx4;   // 16x16 MFMA C/D
typedef __attribute__((ext_vector_type(16))) float floatx16; // 32x32 MFMA C/D

__device__ __forceinline__ short f2bf(float f) {
    unsigned u = __float_as_uint(f);
    u = (u + 0x7FFFu + ((u >> 16) & 1u)) >> 16;
    return (short)u;
}
__device__ __forceinline__ float bf2f(short s) {
    return __uint_as_float(((unsigned)(unsigned short)s) << 16);
}
// raw v_exp_f32 (2^x)
__device__ __forceinline__ float exp2_raw(float x) {
    return __builtin_amdgcn_exp2f(x);
}
// pack two floats to two bf16: a -> low16, b -> high16 (RNE, 1 instr)
__device__ __forceinline__ unsigned pkbf2(float a, float b) {
    unsigned d;
    asm("v_cvt_pk_bf16_f32 %0, %1, %2" : "=v"(d) : "v"(a), "v"(b));
    return d;
}
// async global->LDS, 16 B per lane; LDS dest = wave-uniform base + lane*16
__device__ __forceinline__ void gl2lds16(const short* g, short* l) {
    __builtin_amdgcn_global_load_lds(
        (const __attribute__((address_space(1))) void*)g,
        (__attribute__((address_space(3))) void*)l, 16, 0, 0);
}

// ---------------------------------------------------------------------------
// prep kernel: fused {hs fp32->bf16 | weights fp32->bf16 | depthwise conv}.
// Block ranges: [0,4096) cvt_hs, [4096,4768) cvt_w, [4768,6816) dwconv.
// ---------------------------------------------------------------------------
__global__ __launch_bounds__(256) void prep_kernel(
    const float* __restrict__ hs,
    const float* __restrict__ pw, const float* __restrict__ Wco,
    const float* __restrict__ Wq, const float* __restrict__ Wk,
    const float* __restrict__ Wv, const float* __restrict__ Wck,
    const float* __restrict__ dw,
    short* __restrict__ hsb, short* __restrict__ wb, short* __restrict__ x1)
{
    __shared__ float wl[KW * AD];            // 18 KB (dwconv branch only)
    const int bid = blockIdx.x, tid = threadIdx.x;

    if (bid < 4096) {
        // ---- cvt_hs: MTOK x 1024 fp32 -> bf16, 8 elem/thread ----
        int idx = bid * 256 + tid;
        const float* s = hs + (long)idx * 8;
        float4 a = *(const float4*)s, c = *(const float4*)(s + 4);
        short8 o;
        o[0]=f2bf(a.x); o[1]=f2bf(a.y); o[2]=f2bf(a.z); o[3]=f2bf(a.w);
        o[4]=f2bf(c.x); o[5]=f2bf(c.y); o[6]=f2bf(c.z); o[7]=f2bf(c.w);
        *(short8*)(hsb + (long)idx * 8) = o;
    } else if (bid < 4768) {
        // ---- cvt_w: [pw][Wco][Wq][Wk][Wv][Wck padded 128x512] ----
        int idx = (bid - 4096) * 256 + tid;  // [0, 172032)
        int e0 = idx * 8;
        short8 o;
        if (e0 < 5 * WSZ) {
            int w = e0 >> 18, off = e0 & (WSZ - 1);
            const float* src = (w == 0) ? pw : (w == 1) ? Wco : (w == 2) ? Wq
                             : (w == 3) ? Wk : Wv;
            float4 a = *(const float4*)(src + off), c = *(const float4*)(src + off + 4);
            o[0]=f2bf(a.x); o[1]=f2bf(a.y); o[2]=f2bf(a.z); o[3]=f2bf(a.w);
            o[4]=f2bf(c.x); o[5]=f2bf(c.y); o[6]=f2bf(c.z); o[7]=f2bf(c.w);
        } else {
            int off = e0 - 5 * WSZ;          // 0 .. 65535 over 128x512
            int row = off >> 9, col = off & 511;
            if (row < NH * KW) {
                const float* src = Wck + row * AD + col;
                float4 a = *(const float4*)src, c = *(const float4*)(src + 4);
                o[0]=f2bf(a.x); o[1]=f2bf(a.y); o[2]=f2bf(a.z); o[3]=f2bf(a.w);
                o[4]=f2bf(c.x); o[5]=f2bf(c.y); o[6]=f2bf(c.z); o[7]=f2bf(c.w);
            } else {
                for (int i = 0; i < 8; ++i) o[i] = 0;
            }
        }
        *(short8*)(wb + e0) = o;
    } else {
        // ---- dwconv: 8 ch/thread, fp32 inputs, dw staged transposed ----
        for (int t = tid; t < KW * AD; t += 256) {
            int c = t / KW, k = t - c * KW;  // dw linear = [c][k]
            wl[k * AD + c] = dw[t];
        }
        __syncthreads();
        int idx = (bid - 4768) * 256 + tid;  // over MTOK*AD/8
        int c8  = (idx & 63) * 8;
        int tok = idx >> 6;
        int s   = tok & (SS - 1);
        int b   = tok >> 11;
        const float* base = hs + (long)(b * SS) * HIDD + AD + c8;
        float acc[8];
#pragma unroll
        for (int i = 0; i < 8; ++i) acc[i] = 0.f;
#pragma unroll
        for (int kk = 0; kk < KW; ++kk) {
            int ss2 = s + kk - KW / 2;
            if (ss2 >= 0 && ss2 < SS) {
                const float* hp = base + (long)ss2 * HIDD;
                float4 h0 = *(const float4*)hp;
                float4 h1 = *(const float4*)(hp + 4);
                float4 w0 = *(const float4*)(wl + kk * AD + c8);
                float4 w1 = *(const float4*)(wl + kk * AD + c8 + 4);
                acc[0] += w0.x * h0.x; acc[1] += w0.y * h0.y;
                acc[2] += w0.z * h0.z; acc[3] += w0.w * h0.w;
                acc[4] += w1.x * h1.x; acc[5] += w1.y * h1.y;
                acc[6] += w1.z * h1.z; acc[7] += w1.w * h1.w;
            }
        }
        short8 o;
#pragma unroll
        for (int i = 0; i < 8; ++i) o[i] = f2bf(acc[i]);
        *(short8*)(x1 + (long)tok * AD + c8) = o;
    }
}

// ---------------------------------------------------------------------------
// bf16 MFMA GEMM body v2: software-pipelined (flash-v7 pattern).
// Double-buffered LDS slots; stage(t+1) issued BEFORE compute(t); single raw
// s_barrier per K-step with vmcnt(0) placed AFTER the compute so the staging
// latency hides under ds_read+MFMA (issue-early/wait-late). Tail step
// computes without staging. Sm = base of 2*(TM+TN)*64 shorts.
// MODE 0: fp32 out, bias b0.  MODE 1: bf16 out, bias b0, *oscale.
// MODE 2: bf16 out, bias b0, * bf16 mulp[m*mul_ld+mul_off+n].
// MODE 3: qkv fused (N=1536): n<512 q (bias b0, *oscale); 512..1023 k
//         (bias b1); n>=1024 V -> vT[b][h][d][s] PLAIN key order.
// ---------------------------------------------------------------------------
template<int FM, int FN, int MODE>
__device__ __forceinline__ void gemm_body(
    int bx, int by, short* Sm,
    const short* __restrict__ X, int ldx, int xoff,
    const short* __restrict__ W,
    const float* __restrict__ b0p, const float* __restrict__ b1p,
    const float* __restrict__ b2p,
    const short* __restrict__ mulp, int mul_ld, int mul_off,
    void* __restrict__ Cout, short* __restrict__ vtout,
    int ldc, int N, int Kd, float oscale)
{
    constexpr int TM = 32 * FM, TN = 32 * FN;
    constexpr int SLOT = (TM + TN) * 64;     // shorts per slot
    const int tid  = threadIdx.x;
    const int wv   = tid >> 6, lane = tid & 63;
    const int ln   = lane & 15, quad = lane >> 4;
    const int wm   = wv >> 1, wn = wv & 1;
    const int m0 = bx * TM, n0 = by * TN;

    floatx4 acc[FM][FN];
#pragma unroll
    for (int i = 0; i < FM; ++i)
#pragma unroll
        for (int j = 0; j < FN; ++j) acc[i][j] = (floatx4){0.f, 0.f, 0.f, 0.f};

    const short* xbase = X + (long)m0 * ldx + xoff;
    const short* wbase = W + (long)n0 * Kd;

    auto stage = [&](int k0, int slot) {
        short* As = Sm + slot * SLOT;
        short* Bs = As + TM * 64;
#pragma unroll
        for (int g = tid; g < TM * 8; g += 256) {
            int m = g >> 3, p = g & 7, gk = p ^ (m & 7);
            gl2lds16(xbase + (long)m * ldx + k0 + gk * 8, &As[g * 8]);
        }
#pragma unroll
        for (int g = tid; g < TN * 8; g += 256) {
            int m = g >> 3, p = g & 7, gk = p ^ (m & 7);
            gl2lds16(wbase + (long)m * Kd + k0 + gk * 8, &Bs[g * 8]);
        }
    };
    auto compute = [&](int slot) {
        const short* As = Sm + slot * SLOT;
        const short* Bs = As + TM * 64;
#pragma unroll
        for (int half = 0; half < 2; ++half) {
            short8 afr[FM], bfr[FN];
#pragma unroll
            for (int i = 0; i < FM; ++i) {
                int p = (half * 4 + quad) ^ (ln & 7);
                afr[i] = *(const short8*)&As[(wm * 16 * FM + i * 16 + ln) * 64 + p * 8];
            }
#pragma unroll
            for (int j = 0; j < FN; ++j) {
                int p = (half * 4 + quad) ^ (ln & 7);
                bfr[j] = *(const short8*)&Bs[(wn * 16 * FN + j * 16 + ln) * 64 + p * 8];
            }
#pragma unroll
            for (int i = 0; i < FM; ++i)
#pragma unroll
                for (int j = 0; j < FN; ++j)
                    acc[i][j] = __builtin_amdgcn_mfma_f32_16x16x32_bf16(
                        afr[i], bfr[j], acc[i][j], 0, 0, 0);
        }
    };

    // prologue: stage K-step 0 into slot 0, drain once
    stage(0, 0);
    asm volatile("s_waitcnt vmcnt(0)" ::: "memory");
    __builtin_amdgcn_s_barrier();
    asm volatile("" ::: "memory");

    const int nk = Kd >> 6;
    int slot = 0;
    for (int t = 0; t < nk - 1; ++t) {
        stage((t + 1) * 64, slot ^ 1);   // issue-early: next tile in flight
        compute(slot);                   // latency hides under ds_read+MFMA
        asm volatile("s_waitcnt vmcnt(0)" ::: "memory"); // next tile landed
        __builtin_amdgcn_s_barrier();    // all waves done w/ slot, see slot^1
        asm volatile("" ::: "memory");
        slot ^= 1;
    }
    compute(slot);                       // tail: no staging

#pragma unroll
    for (int j = 0; j < FN; ++j) {
        int n = n0 + wn * 16 * FN + j * 16 + ln;
        if constexpr (MODE == 3) {
            if (n >= 1024) {
                // V third -> vT PLAIN key order, 8B packed stores.
                int hh = (n - 1024) >> 6, dd = (n - 1024) & 63;
                float bv = b2p[n - 1024];
                int mblk = m0 + wm * 16 * FM;             // 64-aligned (FM=4)
                int bidx = mblk >> 11, sblk = mblk & (SS - 1);
                short* dst = vtout + ((long)((bidx * NH + hh) * HD + dd)) * SS + sblk;
#pragma unroll
                for (int i = 0; i < FM; ++i) {
                    unsigned lo = pkbf2(acc[i][j][0] + bv, acc[i][j][1] + bv);
                    unsigned hi = pkbf2(acc[i][j][2] + bv, acc[i][j][3] + bv);
                    *(uint2*)(dst + i * 16 + quad * 4) = make_uint2(lo, hi);
                }
            } else {
                float bv = (n < 512) ? b0p[n] : b1p[n - 512];
                float sc = (n < 512) ? oscale : 1.f;
#pragma unroll
                for (int i = 0; i < FM; ++i) {
#pragma unroll
                    for (int r = 0; r < 4; ++r) {
                        int m = m0 + wm * 16 * FM + i * 16 + quad * 4 + r;
                        float val = (acc[i][j][r] + bv) * sc;
                        ((short*)Cout)[(long)m * ldc + n] = f2bf(val);
                    }
                }
            }
        } else if (n < N) {
            float bv = b0p[n], sc = oscale;
#pragma unroll
            for (int i = 0; i < FM; ++i) {
#pragma unroll
                for (int r = 0; r < 4; ++r) {
                    int m = m0 + wm * 16 * FM + i * 16 + quad * 4 + r;
                    float val = (acc[i][j][r] + bv) * sc;
                    if constexpr (MODE == 2)
                        val *= bf2f(mulp[(long)m * mul_ld + mul_off + n]);
                    if constexpr (MODE == 0)
                        ((float*)Cout)[(long)m * ldc + n] = val;
                    else
                        ((short*)Cout)[(long)m * ldc + n] = f2bf(val);
                }
            }
        }
    }
}

// ---------------------------------------------------------------------------
// mega1: qkv GEMM (768 blocks, FM4/FN4, mode3, dbuf 64 KB) || pointwise
// conv_attn GEMM (512 blocks, FM4/FN2, mode2 -> cabO strided in d_out).
// ---------------------------------------------------------------------------
__global__ __launch_bounds__(256) void mega1_kernel(
    const short* __restrict__ hsb, const short* __restrict__ x1c,
    const short* __restrict__ Wqkv_b, const short* __restrict__ pw_b,
    const float* __restrict__ bq, const float* __restrict__ bk,
    const float* __restrict__ bv, const float* __restrict__ sepb,
    short* __restrict__ qkvb, short* __restrict__ vTb,
    short* __restrict__ cabO, float oscale)
{
    __shared__ __align__(16) char smem[65536];   // 2 slots FM4/FN4
    int bid = blockIdx.x;
    if (bid < 768) {          // qkv: grid (64, 12)
        gemm_body<4, 4, 3>(bid & 63, bid >> 6, (short*)smem,
            hsb, HIDD, 0, Wqkv_b, bq, bk, bv, nullptr, 0, 0,
            qkvb, vTb, 1536, 1536, AD, oscale);
    } else {                  // pointwise: grid (64, 8), ldc = 2048 (strided)
        int id = bid - 768;
        gemm_body<4, 2, 2>(id & 63, id >> 6, (short*)smem,
            x1c, AD, 0, pw_b, sepb, nullptr, nullptr, hsb, HIDD, AD,
            cabO, nullptr, 2048, AD, AD, 1.f);
    }
}

// ---------------------------------------------------------------------------
// mega3: flash attention v8 (blocks [0,512), 4 waves, 128 q-rows) ||
// col GEMM (blocks [512,1024), FM4/FN2 dbuf, mode1) || ckl GEMM (blocks
// [1024,1280), FM2/FN2 dbuf, mode0, A = cabO strided ldx=2048).
// All three depend only on mega1.
// ---------------------------------------------------------------------------
__global__ __launch_bounds__(256) void mega3_kernel(
    const short* __restrict__ qkv, const short* __restrict__ vT,
    const short* __restrict__ hsb, const short* __restrict__ cabO,
    const short* __restrict__ Wco_b, const short* __restrict__ Wck_b,
    const float* __restrict__ bco, const float* __restrict__ bck,
    short* __restrict__ x1c, float* __restrict__ cklp,
    float* __restrict__ out)
{
    __shared__ __align__(16) char smem[49664];
    const int bid = blockIdx.x;
    const int tid = threadIdx.x;

    if (bid >= 512) {
        if (bid < 1024) {     // col: grid (64, 8), dbuf 48 KB
            int id = bid - 512;
            gemm_body<4, 2, 1>(id & 63, id >> 6, (short*)smem,
                hsb, HIDD, AD, Wco_b, bco, nullptr, nullptr, nullptr, 0, 0,
                x1c, nullptr, AD, AD, AD, 1.f);
        } else {              // ckl: grid (128, 2), A strided ldx=2048
            int id = bid - 1024;
            gemm_body<2, 2, 0>(id & 127, id >> 7, (short*)smem,
                cabO, 2048, 0, Wck_b, bck, nullptr, nullptr, nullptr, 0, 0,
                cklp, nullptr, NH * KW, NH * KW, AD, 1.f);
        }
        return;
    }

    // ================= flash v8 branch (identical to round-9 kernel) ======
    short* const KbB = (short*)smem;                 // 3 slots x 4096 shorts
    short* const VbB = (short*)smem + 3 * 4096;      // 3 slots x 4096 shorts
    float* const ls  = (float*)(smem + 49152);       // [4][32]

    const int qt = bid & 15, h = (bid >> 4) & 7, b = bid >> 7;
    const int w    = tid >> 6;        // wave 0..3
    const int lane = tid & 63;
    const int l5   = lane & 31;
    const int hh   = lane >> 5;

    const int  q0 = qt * 128 + w * 32;            // 32 q-rows per wave
    const long rowbase = (long)b * SS;

    // Q resident in regs: lane holds Q[q0+l5][ d = i*16 + hh*8 + 0..7 ]
    short8 qf[4];
    {
        const short* qrow = qkv + (rowbase + q0 + l5) * 1536 + h * HD;
#pragma unroll
        for (int i = 0; i < 4; ++i)
            qf[i] = *(const short8*)(qrow + i * 16 + hh * 8);
    }

    floatx16 acc0, acc1;          // ctx, d 0..31 / 32..63
    floatx16 Z;                   // persistent zero C-in for QK^T
#pragma unroll
    for (int r = 0; r < 16; ++r) { acc0[r] = 0.f; acc1[r] = 0.f; Z[r] = 0.f; }
    float l_i = 0.f;

    // hoisted staging pointers: thread handles granules g1=tid, g2=tid+256
    const int m1 = tid >> 3,  gk1 = (tid & 7) ^ (m1 & 7);
    const int g2 = 256 + tid;
    const int m2 = g2 >> 3,   gk2 = (g2 & 7) ^ (m2 & 7);
    const short* kbase  = qkv + 512 + rowbase * 1536 + h * HD;
    const short* vtbase = vT + ((long)(b * NH + h) * HD) * SS;
    const short* sk0 = kbase  + (long)m1 * 1536 + gk1 * 8;
    const short* sk1 = kbase  + (long)m2 * 1536 + gk2 * 8;
    const short* sv0 = vtbase + (long)m1 * SS   + gk1 * 8;
    const short* sv1 = vtbase + (long)m2 * SS   + gk2 * 8;

    auto STAGE_K = [&](int slot, bool adv) {
        gl2lds16(sk0, KbB + slot * 4096 + tid * 8);
        gl2lds16(sk1, KbB + slot * 4096 + g2 * 8);
        if (adv) { sk0 += 64 * 1536; sk1 += 64 * 1536; }
    };
    auto STAGE_V = [&](int slot) {
        gl2lds16(sv0, VbB + slot * 4096 + tid * 8);
        gl2lds16(sv1, VbB + slot * 4096 + g2 * 8);
        sv0 += 64; sv1 += 64;
    };

    // ---- S^T = K Q^T (8 MFMA, C-in = Z on first d-slice) ----
    auto qkt = [&](const short* KB, floatx16& S0, floatx16& S1) {
        {
            int p = hh ^ (l5 & 7);
            short8 k0 = *(const short8*)&KB[l5 * 64 + p * 8];
            short8 k1 = *(const short8*)&KB[(32 + l5) * 64 + p * 8];
            S0 = __builtin_amdgcn_mfma_f32_32x32x16_bf16(k0, qf[0], Z, 0, 0, 0);
            S1 = __builtin_amdgcn_mfma_f32_32x32x16_bf16(k1, qf[0], Z, 0, 0, 0);
        }
#pragma unroll
        for (int i = 1; i < 4; ++i) {               // d-slice 16i..16i+15
            int p = (2 * i + hh) ^ (l5 & 7);
            short8 k0 = *(const short8*)&KB[l5 * 64 + p * 8];
            short8 k1 = *(const short8*)&KB[(32 + l5) * 64 + p * 8];
            S0 = __builtin_amdgcn_mfma_f32_32x32x16_bf16(k0, qf[i], S0, 0, 0, 0);
            S1 = __builtin_amdgcn_mfma_f32_32x32x16_bf16(k1, qf[i], S1, 0, 0, 0);
        }
    };

    // ---- exp2 + partial l + pack P into PV A-frags (regs only) ----
    auto smax = [&](const floatx16& S0, const floatx16& S1, short8* pf) {
        float pe0[16], pe1[16];
#pragma unroll
        for (int r = 0; r < 16; ++r) {
            pe0[r] = exp2_raw(S0[r]);
            pe1[r] = exp2_raw(S1[r]);
        }
        float s = 0.f;
#pragma unroll
        for (int r = 0; r < 16; ++r) s += pe0[r] + pe1[r];
        l_i += s;
#pragma unroll
        for (int t = 0; t < 2; ++t) {
            const float* pe = t ? pe1 : pe0;
#pragma unroll
            for (int u = 0; u < 2; ++u) {
                unsigned a0 = pkbf2(pe[8 * u + 0], pe[8 * u + 1]);
                unsigned a1 = pkbf2(pe[8 * u + 2], pe[8 * u + 3]);
                unsigned b0 = pkbf2(pe[8 * u + 4], pe[8 * u + 5]);
                unsigned b1 = pkbf2(pe[8 * u + 6], pe[8 * u + 7]);
                asm("v_permlane32_swap_b32 %0, %1" : "+v"(a0), "+v"(b0));
                asm("v_permlane32_swap_b32 %0, %1" : "+v"(a1), "+v"(b1));
                union { uint4 u4; short8 s8; } cv;
                cv.u4 = make_uint4(a0, a1, b0, b1);
                pf[t * 2 + u] = cv.s8;
            }
        }
    };

    // ---- ctx += P V (8 MFMA; P frags in regs) ----
    auto pv = [&](const short* VB, const short8* pf) {
#pragma unroll
        for (int s = 0; s < 4; ++s) {               // key-slice 16s..16s+15
            int p = (2 * s + hh) ^ (l5 & 7);
            short8 v0 = *(const short8*)&VB[l5 * 64 + p * 8];
            short8 v1 = *(const short8*)&VB[(32 + l5) * 64 + p * 8];
            acc0 = __builtin_amdgcn_mfma_f32_32x32x16_bf16(pf[s], v0, acc0, 0, 0, 0);
            acc1 = __builtin_amdgcn_mfma_f32_32x32x16_bf16(pf[s], v1, acc1, 0, 0, 0);
        }
    };

    short8 pfA[4], pfB[4];

    // pre-prologue: K(0)->slot0, K(1)->slot1, V(0)->slot0; full drain
    STAGE_K(0, true);
    STAGE_K(1, true);
    STAGE_V(0);
    asm volatile("s_waitcnt vmcnt(0)" ::: "memory");
    __builtin_amdgcn_s_barrier();
    asm volatile("" ::: "memory");

    // phase 0: qkt(0) only; stage K(2)->slot2, V(1)->slot1
    {
        STAGE_K(2, true);
        STAGE_V(1);
        floatx16 S0, S1;
        qkt(KbB, S0, S1);
        smax(S0, S1, pfA);
        asm volatile("s_waitcnt vmcnt(4)" ::: "memory");
        __builtin_amdgcn_s_barrier();
        asm volatile("" ::: "memory");
    }

    // phases t = 6g+1 .. 6g+6, g = 0..4 (t = 1..30)
#define PHASE(KS, VPS, KST, VST, KADV, PIN, POUT)                      \
    {                                                                  \
        STAGE_K(KST, KADV);                                            \
        STAGE_V(VST);                                                  \
        floatx16 S0, S1;                                               \
        __builtin_amdgcn_s_setprio(1);                                 \
        qkt(KbB + (KS) * 4096, S0, S1);                                \
        pv(VbB + (VPS) * 4096, PIN);                                   \
        __builtin_amdgcn_s_setprio(0);                                 \
        smax(S0, S1, POUT);                                            \
        asm volatile("s_waitcnt vmcnt(4)" ::: "memory");               \
        __builtin_amdgcn_s_barrier();                                  \
        asm volatile("" ::: "memory");                                 \
    }

    for (int g = 0; g < 5; ++g) {
        bool notlast = (g < 4);
        PHASE(1, 0, 0, 2, true,    pfA, pfB);   // t = 6g+1
        PHASE(2, 1, 1, 0, true,    pfB, pfA);   // t = 6g+2
        PHASE(0, 2, 2, 1, true,    pfA, pfB);   // t = 6g+3
        PHASE(1, 0, 0, 2, true,    pfB, pfA);   // t = 6g+4
        PHASE(2, 1, 1, 0, notlast, pfA, pfB);   // t = 6g+5 (t=29: no adv)
        PHASE(0, 2, 2, 1, notlast, pfB, pfA);   // t = 6g+6 (t=30: re-issue K31)
    }
#undef PHASE

    // phase 31: no stages; full drain (retires V(31) staged at t=30)
    {
        floatx16 S0, S1;
        __builtin_amdgcn_s_setprio(1);
        qkt(KbB + 1 * 4096, S0, S1);  // K(31) in slot 31%3=1 (staged t=29)
        pv(VbB + 0 * 4096, pfA);      // V(30) in slot 30%3=0 (staged t=29)
        __builtin_amdgcn_s_setprio(0);
        smax(S0, S1, pfB);
        asm volatile("s_waitcnt vmcnt(0)" ::: "memory");
        __builtin_amdgcn_s_barrier();
        asm volatile("" ::: "memory");
    }
    // final PV(31): V(31) staged t=30 into slot (30+1)%3=1
    pv(VbB + 1 * 4096, pfB);

    // l: halves hold complementary keys of the same q-row
    l_i += __shfl_xor(l_i, 32);
    ls[w * 32 + l5] = 1.f / l_i;    // lanes l5 and l5+32 write same value
    // wave-synchronous LDS (same-wave DS FIFO) - no barrier needed
    float4 lv[4];
#pragma unroll
    for (int g = 0; g < 4; ++g)
        lv[g] = *(const float4*)&ls[w * 32 + 8 * g + 4 * hh];

    // acc layout: col = l5 = d-offset, row(reg r) = (r&3) + 8*(r>>2) + 4*hh
#pragma unroll
    for (int r = 0; r < 16; ++r) {
        int g = r >> 2, j = r & 3;
        int qr = j + 8 * g + 4 * hh;
        float iv = lv[g][j];
        float* orow = out + (rowbase + q0 + qr) * HIDD + h * HD;
        orow[l5]      = acc0[r] * iv;
        orow[32 + l5] = acc1[r] * iv;
    }
}

// ---------------------------------------------------------------------------
// conv_out, 8 channels/thread (one head's 8-ch slice; softmax9 computed once
// per thread, uint4 col taps, 2x float4 stores).
// ---------------------------------------------------------------------------
__global__ __launch_bounds__(256) void convout_kernel(
    const short* __restrict__ col, const float* __restrict__ ckl,
    float* __restrict__ out)
{
    int idx = blockIdx.x * 256 + threadIdx.x;   // over MTOK*AD/8
    int d8  = (idx & 63) * 8;                   // channel octet (0..504)
    int tok = idx >> 6;
    int s   = tok & (SS - 1);
    int b   = tok >> 11;
    int h   = d8 >> 6;
    const float* lg = ckl + (long)tok * (NH * KW) + h * KW;
    float wv[KW];
    float mx = -1e30f;
#pragma unroll
    for (int i = 0; i < KW; ++i) { wv[i] = lg[i]; mx = fmaxf(mx, wv[i]); }
    float sum = 0.f;
#pragma unroll
    for (int i = 0; i < KW; ++i) { wv[i] = __expf(wv[i] - mx); sum += wv[i]; }
    float inv = 1.f / sum;
    float a[8];
#pragma unroll
    for (int i = 0; i < 8; ++i) a[i] = 0.f;
    const short* cbase = col + (long)(b * SS) * AD + d8;
#pragma unroll
    for (int kk = 0; kk < KW; ++kk) {
        int ss2 = s + kk - KW / 2;
        if (ss2 >= 0 && ss2 < SS) {
            uint4 cv = *(const uint4*)(cbase + (long)ss2 * AD);
            float w = wv[kk];
            a[0] += w * bf2f((short)(cv.x & 0xFFFF));
            a[1] += w * bf2f((short)(cv.x >> 16));
            a[2] += w * bf2f((short)(cv.y & 0xFFFF));
            a[3] += w * bf2f((short)(cv.y >> 16));
            a[4] += w * bf2f((short)(cv.z & 0xFFFF));
            a[5] += w * bf2f((short)(cv.z >> 16));
            a[6] += w * bf2f((short)(cv.w & 0xFFFF));
            a[7] += w * bf2f((short)(cv.w >> 16));
        }
    }
    float* op = &out[(long)tok * HIDD + AD + d8];
    *(float4*)op       = make_float4(a[0]*inv, a[1]*inv, a[2]*inv, a[3]*inv);
    *(float4*)(op + 4) = make_float4(a[4]*inv, a[5]*inv, a[6]*inv, a[7]*inv);
}

// ---------------------------------------------------------------------------
extern "C" void kernel_launch(void* const* d_in, const int* in_sizes, int n_in,
                              void* d_out, int out_size, void* d_ws, size_t ws_size,
                              hipStream_t stream)
{
    const float* hs   = (const float*)d_in[0];
    const float* Wq   = (const float*)d_in[1];
    const float* bq   = (const float*)d_in[2];
    const float* Wk   = (const float*)d_in[3];
    const float* bk   = (const float*)d_in[4];
    const float* Wv   = (const float*)d_in[5];
    const float* bv   = (const float*)d_in[6];
    const float* dw   = (const float*)d_in[7];
    const float* pw   = (const float*)d_in[8];
    const float* sepb = (const float*)d_in[9];
    const float* Wck  = (const float*)d_in[10];
    const float* bck  = (const float*)d_in[11];
    const float* Wco  = (const float*)d_in[12];
    const float* bco  = (const float*)d_in[13];
    float* out = (float*)d_out;

    // workspace (bf16 shorts unless noted)
    short* hsb  = (short*)d_ws;                       // MTOK x 1024
    short* x1c  = hsb + (long)MTOK * HIDD;            // MTOK x 512 (x1, then col)
    short* qkvb = x1c + (long)MTOK * AD;              // MTOK x 1536
    short* vTb  = qkvb + (long)MTOK * 1536;           // [b][h][d][s] MTOK*512
    float* ckl  = (float*)(vTb + (long)MTOK * AD);    // MTOK x 72 fp32 logits
    short* wb   = (short*)(ckl + (long)MTOK * (NH * KW));
    short* pw_b   = wb;
    short* Wco_b  = wb + 1L * WSZ;
    short* Wqkv_b = wb + 2L * WSZ;                    // [Wq;Wk;Wv] 1536 x 512
    short* Wck_b  = wb + 5L * WSZ;                    // 128 x 512 (padded)
    // conv_attn scratch: STRIDED into d_out's second-half columns.
    // Element (m,n) at ((short*)out)[m*2048 + 1024 + n] -- bytes [2048,3072)
    // of each 4096-B row. Flash (mega3) writes only fp32 cols [0,512) =
    // bytes [0,2048) -> disjoint. convout overwrites the region only in L4,
    // after ckl consumed it in L3.
    short* cabO   = (short*)d_out + 1024;             // ld = 2048 shorts

    const float QSCALE = 0.18033688011112042f;        // log2(e)/8

    // L1: fused conversions + depthwise conv (mutually independent branches)
    prep_kernel<<<6816, 256, 0, stream>>>(
        hs, pw, Wco, Wq, Wk, Wv, Wck, dw, hsb, wb, x1c);
    // L2: qkv GEMM || pointwise conv_attn GEMM (cabO strided, ldc=2048)
    mega1_kernel<<<1280, 256, 0, stream>>>(
        hsb, x1c, Wqkv_b, pw_b, bq, bk, bv, sepb, qkvb, vTb, cabO, QSCALE);
    // L3: flash attention (512) || col GEMM (512) || ckl GEMM (256)
    mega3_kernel<<<1280, 256, 0, stream>>>(
        qkvb, vTb, hsb, cabO, Wco_b, Wck_b, bco, bck, x1c, ckl, out);
    // L4: windowed mix w/ fused softmax9 -> out[..., 512:]
    convout_kernel<<<MTOK * AD / 2048, 256, 0, stream>>>(x1c, ckl, out);

    (void)in_sizes; (void)n_in; (void)out_size; (void)ws_size;
}

// Round 12
// 200.812 us; speedup vs baseline: 1.1115x; 1.0351x over previous
//
#include <hip/hip_runtime.h>
#include <hip/hip_bf16.h>

// Problem constants (ConvBertSelfAttention): B=4, S=2048, H=8, D=64, K=9
#define NH   8
#define HD   64
#define KW   9
#define AD   512      // H*D
#define HIDD 1024     // 2*A
#define BB   4
#define SS   2048
#define MTOK (BB*SS)  // 8192 tokens
#define WSZ  262144   // 512*512 weight elements

typedef __attribute__((ext_vector_type(8))) short short8;    // 8 bf16 (4 VGPRs)
typedef __attribute__((ext_vector_type(4))) float floatx4;   // 16x16 MFMA C/D
typedef __attribute__((ext_vector_type(16))) float floatx16; // 32x32 MFMA C/D

__device__ __forceinline__ short f2bf(float f) {
    unsigned u = __float_as_uint(f);
    u = (u + 0x7FFFu + ((u >> 16) & 1u)) >> 16;
    return (short)u;
}
__device__ __forceinline__ float bf2f(short s) {
    return __uint_as_float(((unsigned)(unsigned short)s) << 16);
}
// raw v_exp_f32 (2^x)
__device__ __forceinline__ float exp2_raw(float x) {
    return __builtin_amdgcn_exp2f(x);
}
// pack two floats to two bf16: a -> low16, b -> high16 (RNE, 1 instr)
__device__ __forceinline__ unsigned pkbf2(float a, float b) {
    unsigned d;
    asm("v_cvt_pk_bf16_f32 %0, %1, %2" : "=v"(d) : "v"(a), "v"(b));
    return d;
}
// async global->LDS, 16 B per lane; LDS dest = wave-uniform base + lane*16
__device__ __forceinline__ void gl2lds16(const short* g, short* l) {
    __builtin_amdgcn_global_load_lds(
        (const __attribute__((address_space(1))) void*)g,
        (__attribute__((address_space(3))) void*)l, 16, 0, 0);
}

// ---------------------------------------------------------------------------
// prep kernel: fused {hs fp32->bf16 | weights fp32->bf16 | depthwise conv}.
// Block ranges: [0,4096) cvt_hs, [4096,4768) cvt_w, [4768,6816) dwconv.
// ---------------------------------------------------------------------------
__global__ __launch_bounds__(256) void prep_kernel(
    const float* __restrict__ hs,
    const float* __restrict__ pw, const float* __restrict__ Wco,
    const float* __restrict__ Wq, const float* __restrict__ Wk,
    const float* __restrict__ Wv, const float* __restrict__ Wck,
    const float* __restrict__ dw,
    short* __restrict__ hsb, short* __restrict__ wb, short* __restrict__ x1)
{
    __shared__ float wl[KW * AD];            // 18 KB (dwconv branch only)
    const int bid = blockIdx.x, tid = threadIdx.x;

    if (bid < 4096) {
        // ---- cvt_hs: MTOK x 1024 fp32 -> bf16, 8 elem/thread ----
        int idx = bid * 256 + tid;
        const float* s = hs + (long)idx * 8;
        float4 a = *(const float4*)s, c = *(const float4*)(s + 4);
        short8 o;
        o[0]=f2bf(a.x); o[1]=f2bf(a.y); o[2]=f2bf(a.z); o[3]=f2bf(a.w);
        o[4]=f2bf(c.x); o[5]=f2bf(c.y); o[6]=f2bf(c.z); o[7]=f2bf(c.w);
        *(short8*)(hsb + (long)idx * 8) = o;
    } else if (bid < 4768) {
        // ---- cvt_w: [pw][Wco][Wq][Wk][Wv][Wck padded 128x512] ----
        int idx = (bid - 4096) * 256 + tid;  // [0, 172032)
        int e0 = idx * 8;
        short8 o;
        if (e0 < 5 * WSZ) {
            int w = e0 >> 18, off = e0 & (WSZ - 1);
            const float* src = (w == 0) ? pw : (w == 1) ? Wco : (w == 2) ? Wq
                             : (w == 3) ? Wk : Wv;
            float4 a = *(const float4*)(src + off), c = *(const float4*)(src + off + 4);
            o[0]=f2bf(a.x); o[1]=f2bf(a.y); o[2]=f2bf(a.z); o[3]=f2bf(a.w);
            o[4]=f2bf(c.x); o[5]=f2bf(c.y); o[6]=f2bf(c.z); o[7]=f2bf(c.w);
        } else {
            int off = e0 - 5 * WSZ;          // 0 .. 65535 over 128x512
            int row = off >> 9, col = off & 511;
            if (row < NH * KW) {
                const float* src = Wck + row * AD + col;
                float4 a = *(const float4*)src, c = *(const float4*)(src + 4);
                o[0]=f2bf(a.x); o[1]=f2bf(a.y); o[2]=f2bf(a.z); o[3]=f2bf(a.w);
                o[4]=f2bf(c.x); o[5]=f2bf(c.y); o[6]=f2bf(c.z); o[7]=f2bf(c.w);
            } else {
                for (int i = 0; i < 8; ++i) o[i] = 0;
            }
        }
        *(short8*)(wb + e0) = o;
    } else {
        // ---- dwconv: 8 ch/thread, fp32 inputs, dw staged transposed ----
        for (int t = tid; t < KW * AD; t += 256) {
            int c = t / KW, k = t - c * KW;  // dw linear = [c][k]
            wl[k * AD + c] = dw[t];
        }
        __syncthreads();
        int idx = (bid - 4768) * 256 + tid;  // over MTOK*AD/8
        int c8  = (idx & 63) * 8;
        int tok = idx >> 6;
        int s   = tok & (SS - 1);
        int b   = tok >> 11;
        const float* base = hs + (long)(b * SS) * HIDD + AD + c8;
        float acc[8];
#pragma unroll
        for (int i = 0; i < 8; ++i) acc[i] = 0.f;
#pragma unroll
        for (int kk = 0; kk < KW; ++kk) {
            int ss2 = s + kk - KW / 2;
            if (ss2 >= 0 && ss2 < SS) {
                const float* hp = base + (long)ss2 * HIDD;
                float4 h0 = *(const float4*)hp;
                float4 h1 = *(const float4*)(hp + 4);
                float4 w0 = *(const float4*)(wl + kk * AD + c8);
                float4 w1 = *(const float4*)(wl + kk * AD + c8 + 4);
                acc[0] += w0.x * h0.x; acc[1] += w0.y * h0.y;
                acc[2] += w0.z * h0.z; acc[3] += w0.w * h0.w;
                acc[4] += w1.x * h1.x; acc[5] += w1.y * h1.y;
                acc[6] += w1.z * h1.z; acc[7] += w1.w * h1.w;
            }
        }
        short8 o;
#pragma unroll
        for (int i = 0; i < 8; ++i) o[i] = f2bf(acc[i]);
        *(short8*)(x1 + (long)tok * AD + c8) = o;
    }
}

// ---------------------------------------------------------------------------
// bf16 MFMA GEMM body v2: software-pipelined (flash-v7 pattern).
// Double-buffered LDS slots; stage(t+1) issued BEFORE compute(t); single raw
// s_barrier per K-step with vmcnt(0) AFTER the compute (issue-early/
// wait-late). Tail step computes without staging.
// MODE 0: fp32 out, bias b0.  MODE 1: bf16 out, bias b0, *oscale.
// MODE 2: bf16 out, bias b0, * bf16 mulp[m*mul_ld+mul_off+n].
// MODE 3: qkv fused (N=1536): n<1024 q/k scalar stores; n>=1024 V ->
//         128x128 LDS transpose (Sm reused, [128][130] pad) -> vT
//         [b][h][d][s] in COALESCED 128-B runs (was 16x32B scatter @4KB).
// ---------------------------------------------------------------------------
template<int FM, int FN, int MODE>
__device__ __forceinline__ void gemm_body(
    int bx, int by, short* Sm,
    const short* __restrict__ X, int ldx, int xoff,
    const short* __restrict__ W,
    const float* __restrict__ b0p, const float* __restrict__ b1p,
    const float* __restrict__ b2p,
    const short* __restrict__ mulp, int mul_ld, int mul_off,
    void* __restrict__ Cout, short* __restrict__ vtout,
    int ldc, int N, int Kd, float oscale)
{
    constexpr int TM = 32 * FM, TN = 32 * FN;
    constexpr int SLOT = (TM + TN) * 64;     // shorts per slot
    const int tid  = threadIdx.x;
    const int wv   = tid >> 6, lane = tid & 63;
    const int ln   = lane & 15, quad = lane >> 4;
    const int wm   = wv >> 1, wn = wv & 1;
    const int m0 = bx * TM, n0 = by * TN;

    floatx4 acc[FM][FN];
#pragma unroll
    for (int i = 0; i < FM; ++i)
#pragma unroll
        for (int j = 0; j < FN; ++j) acc[i][j] = (floatx4){0.f, 0.f, 0.f, 0.f};

    const short* xbase = X + (long)m0 * ldx + xoff;
    const short* wbase = W + (long)n0 * Kd;

    auto stage = [&](int k0, int slot) {
        short* As = Sm + slot * SLOT;
        short* Bs = As + TM * 64;
#pragma unroll
        for (int g = tid; g < TM * 8; g += 256) {
            int m = g >> 3, p = g & 7, gk = p ^ (m & 7);
            gl2lds16(xbase + (long)m * ldx + k0 + gk * 8, &As[g * 8]);
        }
#pragma unroll
        for (int g = tid; g < TN * 8; g += 256) {
            int m = g >> 3, p = g & 7, gk = p ^ (m & 7);
            gl2lds16(wbase + (long)m * Kd + k0 + gk * 8, &Bs[g * 8]);
        }
    };
    auto compute = [&](int slot) {
        const short* As = Sm + slot * SLOT;
        const short* Bs = As + TM * 64;
#pragma unroll
        for (int half = 0; half < 2; ++half) {
            short8 afr[FM], bfr[FN];
#pragma unroll
            for (int i = 0; i < FM; ++i) {
                int p = (half * 4 + quad) ^ (ln & 7);
                afr[i] = *(const short8*)&As[(wm * 16 * FM + i * 16 + ln) * 64 + p * 8];
            }
#pragma unroll
            for (int j = 0; j < FN; ++j) {
                int p = (half * 4 + quad) ^ (ln & 7);
                bfr[j] = *(const short8*)&Bs[(wn * 16 * FN + j * 16 + ln) * 64 + p * 8];
            }
#pragma unroll
            for (int i = 0; i < FM; ++i)
#pragma unroll
                for (int j = 0; j < FN; ++j)
                    acc[i][j] = __builtin_amdgcn_mfma_f32_16x16x32_bf16(
                        afr[i], bfr[j], acc[i][j], 0, 0, 0);
        }
    };

    // prologue: stage K-step 0 into slot 0, drain once
    stage(0, 0);
    asm volatile("s_waitcnt vmcnt(0)" ::: "memory");
    __builtin_amdgcn_s_barrier();
    asm volatile("" ::: "memory");

    const int nk = Kd >> 6;
    int slot = 0;
    for (int t = 0; t < nk - 1; ++t) {
        stage((t + 1) * 64, slot ^ 1);   // issue-early: next tile in flight
        compute(slot);                   // latency hides under ds_read+MFMA
        asm volatile("s_waitcnt vmcnt(0)" ::: "memory"); // next tile landed
        __builtin_amdgcn_s_barrier();    // all waves done w/ slot, see slot^1
        asm volatile("" ::: "memory");
        slot ^= 1;
    }
    compute(slot);                       // tail: no staging

    if constexpr (MODE == 3) {
        if (n0 >= 1024) {
            // ---- V block: transpose 128x128 via LDS, coalesced vT stores.
            // T[nl][ml] (pad 130): write <=4-way bank conflict (cheap);
            // read 4B-aligned; global stores 128-B contiguous runs/thread.
            __syncthreads();             // all LDS reads of Sm retired
            short* T = Sm;               // 128*130*2 = 33280 B <= 64 KB smem
#pragma unroll
            for (int j = 0; j < FN; ++j) {
                int nl = wn * 16 * FN + j * 16 + ln;
                float bv = b2p[n0 - 1024 + nl];
#pragma unroll
                for (int i = 0; i < FM; ++i) {
                    int ml = wm * 16 * FM + i * 16 + quad * 4;
                    unsigned lo = pkbf2(acc[i][j][0] + bv, acc[i][j][1] + bv);
                    unsigned hi = pkbf2(acc[i][j][2] + bv, acc[i][j][3] + bv);
                    *(unsigned*)&T[nl * 130 + ml]     = lo;
                    *(unsigned*)&T[nl * 130 + ml + 2] = hi;
                }
            }
            __syncthreads();
            int nl = tid >> 1, hf = tid & 1;           // row, m-half
            int nn = n0 - 1024 + nl;
            int hh2 = nn >> 6, dd = nn & 63;
            int bidx = m0 >> 11, sblk = m0 & (SS - 1);
            short* dst = vtout + ((long)((bidx * NH + hh2) * HD + dd)) * SS
                       + sblk + hf * 64;
            const short* src = &T[nl * 130 + hf * 64];
#pragma unroll
            for (int u = 0; u < 8; ++u) {              // 64 shorts = 8x16B
                uint4 v;
                v.x = *(const unsigned*)&src[u * 8 + 0];
                v.y = *(const unsigned*)&src[u * 8 + 2];
                v.z = *(const unsigned*)&src[u * 8 + 4];
                v.w = *(const unsigned*)&src[u * 8 + 6];
                *(uint4*)(dst + u * 8) = v;
            }
            return;
        }
        // q/k block (n0 < 1024)
#pragma unroll
        for (int j = 0; j < FN; ++j) {
            int n = n0 + wn * 16 * FN + j * 16 + ln;
            float bv = (n < 512) ? b0p[n] : b1p[n - 512];
            float sc = (n < 512) ? oscale : 1.f;
#pragma unroll
            for (int i = 0; i < FM; ++i) {
#pragma unroll
                for (int r = 0; r < 4; ++r) {
                    int m = m0 + wm * 16 * FM + i * 16 + quad * 4 + r;
                    float val = (acc[i][j][r] + bv) * sc;
                    ((short*)Cout)[(long)m * ldc + n] = f2bf(val);
                }
            }
        }
        return;
    }

#pragma unroll
    for (int j = 0; j < FN; ++j) {
        int n = n0 + wn * 16 * FN + j * 16 + ln;
        if (n < N) {
            float bv = b0p[n], sc = oscale;
#pragma unroll
            for (int i = 0; i < FM; ++i) {
#pragma unroll
                for (int r = 0; r < 4; ++r) {
                    int m = m0 + wm * 16 * FM + i * 16 + quad * 4 + r;
                    float val = (acc[i][j][r] + bv) * sc;
                    if constexpr (MODE == 2)
                        val *= bf2f(mulp[(long)m * mul_ld + mul_off + n]);
                    if constexpr (MODE == 0)
                        ((float*)Cout)[(long)m * ldc + n] = val;
                    else
                        ((short*)Cout)[(long)m * ldc + n] = f2bf(val);
                }
            }
        }
    }
}

// ---------------------------------------------------------------------------
// mega1: qkv GEMM (768 blocks, FM4/FN4, mode3, dbuf 64 KB) || pointwise
// conv_attn GEMM (512 blocks, FM4/FN2, mode2 -> cabO strided in d_out).
// ---------------------------------------------------------------------------
__global__ __launch_bounds__(256) void mega1_kernel(
    const short* __restrict__ hsb, const short* __restrict__ x1c,
    const short* __restrict__ Wqkv_b, const short* __restrict__ pw_b,
    const float* __restrict__ bq, const float* __restrict__ bk,
    const float* __restrict__ bv, const float* __restrict__ sepb,
    short* __restrict__ qkvb, short* __restrict__ vTb,
    short* __restrict__ cabO, float oscale)
{
    __shared__ __align__(16) char smem[65536];   // 2 slots FM4/FN4
    int bid = blockIdx.x;
    if (bid < 768) {          // qkv: grid (64, 12)
        gemm_body<4, 4, 3>(bid & 63, bid >> 6, (short*)smem,
            hsb, HIDD, 0, Wqkv_b, bq, bk, bv, nullptr, 0, 0,
            qkvb, vTb, 1536, 1536, AD, oscale);
    } else {                  // pointwise: grid (64, 8), ldc = 2048 (strided)
        int id = bid - 768;
        gemm_body<4, 2, 2>(id & 63, id >> 6, (short*)smem,
            x1c, AD, 0, pw_b, sepb, nullptr, nullptr, hsb, HIDD, AD,
            cabO, nullptr, 2048, AD, AD, 1.f);
    }
}

// ---------------------------------------------------------------------------
// mega3: flash attention v8 (blocks [0,512), 4 waves, 128 q-rows) ||
// col GEMM (blocks [512,1024), FM4/FN2 dbuf, mode1) || ckl GEMM (blocks
// [1024,1280), FM2/FN2 dbuf, mode0, A = cabO strided ldx=2048).
// All three depend only on mega1.
// ---------------------------------------------------------------------------
__global__ __launch_bounds__(256) void mega3_kernel(
    const short* __restrict__ qkv, const short* __restrict__ vT,
    const short* __restrict__ hsb, const short* __restrict__ cabO,
    const short* __restrict__ Wco_b, const short* __restrict__ Wck_b,
    const float* __restrict__ bco, const float* __restrict__ bck,
    short* __restrict__ x1c, float* __restrict__ cklp,
    float* __restrict__ out)
{
    __shared__ __align__(16) char smem[49664];
    const int bid = blockIdx.x;
    const int tid = threadIdx.x;

    if (bid >= 512) {
        if (bid < 1024) {     // col: grid (64, 8), dbuf 48 KB
            int id = bid - 512;
            gemm_body<4, 2, 1>(id & 63, id >> 6, (short*)smem,
                hsb, HIDD, AD, Wco_b, bco, nullptr, nullptr, nullptr, 0, 0,
                x1c, nullptr, AD, AD, AD, 1.f);
        } else {              // ckl: grid (128, 2), A strided ldx=2048
            int id = bid - 1024;
            gemm_body<2, 2, 0>(id & 127, id >> 7, (short*)smem,
                cabO, 2048, 0, Wck_b, bck, nullptr, nullptr, nullptr, 0, 0,
                cklp, nullptr, NH * KW, NH * KW, AD, 1.f);
        }
        return;
    }

    // ================= flash v8 branch (identical to round-10 kernel) =====
    short* const KbB = (short*)smem;                 // 3 slots x 4096 shorts
    short* const VbB = (short*)smem + 3 * 4096;      // 3 slots x 4096 shorts
    float* const ls  = (float*)(smem + 49152);       // [4][32]

    const int qt = bid & 15, h = (bid >> 4) & 7, b = bid >> 7;
    const int w    = tid >> 6;        // wave 0..3
    const int lane = tid & 63;
    const int l5   = lane & 31;
    const int hh   = lane >> 5;

    const int  q0 = qt * 128 + w * 32;            // 32 q-rows per wave
    const long rowbase = (long)b * SS;

    // Q resident in regs: lane holds Q[q0+l5][ d = i*16 + hh*8 + 0..7 ]
    short8 qf[4];
    {
        const short* qrow = qkv + (rowbase + q0 + l5) * 1536 + h * HD;
#pragma unroll
        for (int i = 0; i < 4; ++i)
            qf[i] = *(const short8*)(qrow + i * 16 + hh * 8);
    }

    floatx16 acc0, acc1;          // ctx, d 0..31 / 32..63
    floatx16 Z;                   // persistent zero C-in for QK^T
#pragma unroll
    for (int r = 0; r < 16; ++r) { acc0[r] = 0.f; acc1[r] = 0.f; Z[r] = 0.f; }
    float l_i = 0.f;

    // hoisted staging pointers: thread handles granules g1=tid, g2=tid+256
    const int m1 = tid >> 3,  gk1 = (tid & 7) ^ (m1 & 7);
    const int g2 = 256 + tid;
    const int m2 = g2 >> 3,   gk2 = (g2 & 7) ^ (m2 & 7);
    const short* kbase  = qkv + 512 + rowbase * 1536 + h * HD;
    const short* vtbase = vT + ((long)(b * NH + h) * HD) * SS;
    const short* sk0 = kbase  + (long)m1 * 1536 + gk1 * 8;
    const short* sk1 = kbase  + (long)m2 * 1536 + gk2 * 8;
    const short* sv0 = vtbase + (long)m1 * SS   + gk1 * 8;
    const short* sv1 = vtbase + (long)m2 * SS   + gk2 * 8;

    auto STAGE_K = [&](int slot, bool adv) {
        gl2lds16(sk0, KbB + slot * 4096 + tid * 8);
        gl2lds16(sk1, KbB + slot * 4096 + g2 * 8);
        if (adv) { sk0 += 64 * 1536; sk1 += 64 * 1536; }
    };
    auto STAGE_V = [&](int slot) {
        gl2lds16(sv0, VbB + slot * 4096 + tid * 8);
        gl2lds16(sv1, VbB + slot * 4096 + g2 * 8);
        sv0 += 64; sv1 += 64;
    };

    // ---- S^T = K Q^T (8 MFMA, C-in = Z on first d-slice) ----
    auto qkt = [&](const short* KB, floatx16& S0, floatx16& S1) {
        {
            int p = hh ^ (l5 & 7);
            short8 k0 = *(const short8*)&KB[l5 * 64 + p * 8];
            short8 k1 = *(const short8*)&KB[(32 + l5) * 64 + p * 8];
            S0 = __builtin_amdgcn_mfma_f32_32x32x16_bf16(k0, qf[0], Z, 0, 0, 0);
            S1 = __builtin_amdgcn_mfma_f32_32x32x16_bf16(k1, qf[0], Z, 0, 0, 0);
        }
#pragma unroll
        for (int i = 1; i < 4; ++i) {               // d-slice 16i..16i+15
            int p = (2 * i + hh) ^ (l5 & 7);
            short8 k0 = *(const short8*)&KB[l5 * 64 + p * 8];
            short8 k1 = *(const short8*)&KB[(32 + l5) * 64 + p * 8];
            S0 = __builtin_amdgcn_mfma_f32_32x32x16_bf16(k0, qf[i], S0, 0, 0, 0);
            S1 = __builtin_amdgcn_mfma_f32_32x32x16_bf16(k1, qf[i], S1, 0, 0, 0);
        }
    };

    // ---- exp2 + partial l + pack P into PV A-frags (regs only) ----
    auto smax = [&](const floatx16& S0, const floatx16& S1, short8* pf) {
        float pe0[16], pe1[16];
#pragma unroll
        for (int r = 0; r < 16; ++r) {
            pe0[r] = exp2_raw(S0[r]);
            pe1[r] = exp2_raw(S1[r]);
        }
        float s = 0.f;
#pragma unroll
        for (int r = 0; r < 16; ++r) s += pe0[r] + pe1[r];
        l_i += s;
#pragma unroll
        for (int t = 0; t < 2; ++t) {
            const float* pe = t ? pe1 : pe0;
#pragma unroll
            for (int u = 0; u < 2; ++u) {
                unsigned a0 = pkbf2(pe[8 * u + 0], pe[8 * u + 1]);
                unsigned a1 = pkbf2(pe[8 * u + 2], pe[8 * u + 3]);
                unsigned b0 = pkbf2(pe[8 * u + 4], pe[8 * u + 5]);
                unsigned b1 = pkbf2(pe[8 * u + 6], pe[8 * u + 7]);
                asm("v_permlane32_swap_b32 %0, %1" : "+v"(a0), "+v"(b0));
                asm("v_permlane32_swap_b32 %0, %1" : "+v"(a1), "+v"(b1));
                union { uint4 u4; short8 s8; } cv;
                cv.u4 = make_uint4(a0, a1, b0, b1);
                pf[t * 2 + u] = cv.s8;
            }
        }
    };

    // ---- ctx += P V (8 MFMA; P frags in regs) ----
    auto pv = [&](const short* VB, const short8* pf) {
#pragma unroll
        for (int s = 0; s < 4; ++s) {               // key-slice 16s..16s+15
            int p = (2 * s + hh) ^ (l5 & 7);
            short8 v0 = *(const short8*)&VB[l5 * 64 + p * 8];
            short8 v1 = *(const short8*)&VB[(32 + l5) * 64 + p * 8];
            acc0 = __builtin_amdgcn_mfma_f32_32x32x16_bf16(pf[s], v0, acc0, 0, 0, 0);
            acc1 = __builtin_amdgcn_mfma_f32_32x32x16_bf16(pf[s], v1, acc1, 0, 0, 0);
        }
    };

    short8 pfA[4], pfB[4];

    // pre-prologue: K(0)->slot0, K(1)->slot1, V(0)->slot0; full drain
    STAGE_K(0, true);
    STAGE_K(1, true);
    STAGE_V(0);
    asm volatile("s_waitcnt vmcnt(0)" ::: "memory");
    __builtin_amdgcn_s_barrier();
    asm volatile("" ::: "memory");

    // phase 0: qkt(0) only; stage K(2)->slot2, V(1)->slot1
    {
        STAGE_K(2, true);
        STAGE_V(1);
        floatx16 S0, S1;
        qkt(KbB, S0, S1);
        smax(S0, S1, pfA);
        asm volatile("s_waitcnt vmcnt(4)" ::: "memory");
        __builtin_amdgcn_s_barrier();
        asm volatile("" ::: "memory");
    }

    // phases t = 6g+1 .. 6g+6, g = 0..4 (t = 1..30)
#define PHASE(KS, VPS, KST, VST, KADV, PIN, POUT)                      \
    {                                                                  \
        STAGE_K(KST, KADV);                                            \
        STAGE_V(VST);                                                  \
        floatx16 S0, S1;                                               \
        __builtin_amdgcn_s_setprio(1);                                 \
        qkt(KbB + (KS) * 4096, S0, S1);                                \
        pv(VbB + (VPS) * 4096, PIN);                                   \
        __builtin_amdgcn_s_setprio(0);                                 \
        smax(S0, S1, POUT);                                            \
        asm volatile("s_waitcnt vmcnt(4)" ::: "memory");               \
        __builtin_amdgcn_s_barrier();                                  \
        asm volatile("" ::: "memory");                                 \
    }

    for (int g = 0; g < 5; ++g) {
        bool notlast = (g < 4);
        PHASE(1, 0, 0, 2, true,    pfA, pfB);   // t = 6g+1
        PHASE(2, 1, 1, 0, true,    pfB, pfA);   // t = 6g+2
        PHASE(0, 2, 2, 1, true,    pfA, pfB);   // t = 6g+3
        PHASE(1, 0, 0, 2, true,    pfB, pfA);   // t = 6g+4
        PHASE(2, 1, 1, 0, notlast, pfA, pfB);   // t = 6g+5 (t=29: no adv)
        PHASE(0, 2, 2, 1, notlast, pfB, pfA);   // t = 6g+6 (t=30: re-issue K31)
    }
#undef PHASE

    // phase 31: no stages; full drain (retires V(31) staged at t=30)
    {
        floatx16 S0, S1;
        __builtin_amdgcn_s_setprio(1);
        qkt(KbB + 1 * 4096, S0, S1);  // K(31) in slot 31%3=1 (staged t=29)
        pv(VbB + 0 * 4096, pfA);      // V(30) in slot 30%3=0 (staged t=29)
        __builtin_amdgcn_s_setprio(0);
        smax(S0, S1, pfB);
        asm volatile("s_waitcnt vmcnt(0)" ::: "memory");
        __builtin_amdgcn_s_barrier();
        asm volatile("" ::: "memory");
    }
    // final PV(31): V(31) staged t=30 into slot (30+1)%3=1
    pv(VbB + 1 * 4096, pfB);

    // l: halves hold complementary keys of the same q-row
    l_i += __shfl_xor(l_i, 32);
    ls[w * 32 + l5] = 1.f / l_i;    // lanes l5 and l5+32 write same value
    // wave-synchronous LDS (same-wave DS FIFO) - no barrier needed
    float4 lv[4];
#pragma unroll
    for (int g = 0; g < 4; ++g)
        lv[g] = *(const float4*)&ls[w * 32 + 8 * g + 4 * hh];

    // acc layout: col = l5 = d-offset, row(reg r) = (r&3) + 8*(r>>2) + 4*hh
#pragma unroll
    for (int r = 0; r < 16; ++r) {
        int g = r >> 2, j = r & 3;
        int qr = j + 8 * g + 4 * hh;
        float iv = lv[g][j];
        float* orow = out + (rowbase + q0 + qr) * HIDD + h * HD;
        orow[l5]      = acc0[r] * iv;
        orow[32 + l5] = acc1[r] * iv;
    }
}

// ---------------------------------------------------------------------------
// conv_out, 8 channels/thread (one head's 8-ch slice; softmax9 computed once
// per thread, uint4 col taps, 2x float4 stores).
// ---------------------------------------------------------------------------
__global__ __launch_bounds__(256) void convout_kernel(
    const short* __restrict__ col, const float* __restrict__ ckl,
    float* __restrict__ out)
{
    int idx = blockIdx.x * 256 + threadIdx.x;   // over MTOK*AD/8
    int d8  = (idx & 63) * 8;                   // channel octet (0..504)
    int tok = idx >> 6;
    int s   = tok & (SS - 1);
    int b   = tok >> 11;
    int h   = d8 >> 6;
    const float* lg = ckl + (long)tok * (NH * KW) + h * KW;
    float wv[KW];
    float mx = -1e30f;
#pragma unroll
    for (int i = 0; i < KW; ++i) { wv[i] = lg[i]; mx = fmaxf(mx, wv[i]); }
    float sum = 0.f;
#pragma unroll
    for (int i = 0; i < KW; ++i) { wv[i] = __expf(wv[i] - mx); sum += wv[i]; }
    float inv = 1.f / sum;
    float a[8];
#pragma unroll
    for (int i = 0; i < 8; ++i) a[i] = 0.f;
    const short* cbase = col + (long)(b * SS) * AD + d8;
#pragma unroll
    for (int kk = 0; kk < KW; ++kk) {
        int ss2 = s + kk - KW / 2;
        if (ss2 >= 0 && ss2 < SS) {
            uint4 cv = *(const uint4*)(cbase + (long)ss2 * AD);
            float w = wv[kk];
            a[0] += w * bf2f((short)(cv.x & 0xFFFF));
            a[1] += w * bf2f((short)(cv.x >> 16));
            a[2] += w * bf2f((short)(cv.y & 0xFFFF));
            a[3] += w * bf2f((short)(cv.y >> 16));
            a[4] += w * bf2f((short)(cv.z & 0xFFFF));
            a[5] += w * bf2f((short)(cv.z >> 16));
            a[6] += w * bf2f((short)(cv.w & 0xFFFF));
            a[7] += w * bf2f((short)(cv.w >> 16));
        }
    }
    float* op = &out[(long)tok * HIDD + AD + d8];
    *(float4*)op       = make_float4(a[0]*inv, a[1]*inv, a[2]*inv, a[3]*inv);
    *(float4*)(op + 4) = make_float4(a[4]*inv, a[5]*inv, a[6]*inv, a[7]*inv);
}

// ---------------------------------------------------------------------------
extern "C" void kernel_launch(void* const* d_in, const int* in_sizes, int n_in,
                              void* d_out, int out_size, void* d_ws, size_t ws_size,
                              hipStream_t stream)
{
    const float* hs   = (const float*)d_in[0];
    const float* Wq   = (const float*)d_in[1];
    const float* bq   = (const float*)d_in[2];
    const float* Wk   = (const float*)d_in[3];
    const float* bk   = (const float*)d_in[4];
    const float* Wv   = (const float*)d_in[5];
    const float* bv   = (const float*)d_in[6];
    const float* dw   = (const float*)d_in[7];
    const float* pw   = (const float*)d_in[8];
    const float* sepb = (const float*)d_in[9];
    const float* Wck  = (const float*)d_in[10];
    const float* bck  = (const float*)d_in[11];
    const float* Wco  = (const float*)d_in[12];
    const float* bco  = (const float*)d_in[13];
    float* out = (float*)d_out;

    // workspace (bf16 shorts unless noted)
    short* hsb  = (short*)d_ws;                       // MTOK x 1024
    short* x1c  = hsb + (long)MTOK * HIDD;            // MTOK x 512 (x1, then col)
    short* qkvb = x1c + (long)MTOK * AD;              // MTOK x 1536
    short* vTb  = qkvb + (long)MTOK * 1536;           // [b][h][d][s] MTOK*512
    float* ckl  = (float*)(vTb + (long)MTOK * AD);    // MTOK x 72 fp32 logits
    short* wb   = (short*)(ckl + (long)MTOK * (NH * KW));
    short* pw_b   = wb;
    short* Wco_b  = wb + 1L * WSZ;
    short* Wqkv_b = wb + 2L * WSZ;                    // [Wq;Wk;Wv] 1536 x 512
    short* Wck_b  = wb + 5L * WSZ;                    // 128 x 512 (padded)
    // conv_attn scratch: STRIDED into d_out's second-half columns.
    // Element (m,n) at ((short*)out)[m*2048 + 1024 + n] -- bytes [2048,3072)
    // of each 4096-B row. Flash (mega3) writes only fp32 cols [0,512) =
    // bytes [0,2048) -> disjoint. convout overwrites the region only in L4,
    // after ckl consumed it in L3.
    short* cabO   = (short*)d_out + 1024;             // ld = 2048 shorts

    const float QSCALE = 0.18033688011112042f;        // log2(e)/8

    // L1: fused conversions + depthwise conv (mutually independent branches)
    prep_kernel<<<6816, 256, 0, stream>>>(
        hs, pw, Wco, Wq, Wk, Wv, Wck, dw, hsb, wb, x1c);
    // L2: qkv GEMM || pointwise conv_attn GEMM (cabO strided, ldc=2048)
    mega1_kernel<<<1280, 256, 0, stream>>>(
        hsb, x1c, Wqkv_b, pw_b, bq, bk, bv, sepb, qkvb, vTb, cabO, QSCALE);
    // L3: flash attention (512) || col GEMM (512) || ckl GEMM (256)
    mega3_kernel<<<1280, 256, 0, stream>>>(
        qkvb, vTb, hsb, cabO, Wco_b, Wck_b, bco, bck, x1c, ckl, out);
    // L4: windowed mix w/ fused softmax9 -> out[..., 512:]
    convout_kernel<<<MTOK * AD / 2048, 256, 0, stream>>>(x1c, ckl, out);

    (void)in_sizes; (void)n_in; (void)out_size; (void)ws_size;
}